// Round 3
// baseline (574.963 us; speedup 1.0000x reference)
//
#include <hip/hip_runtime.h>
#include <math.h>

// ---------------------------------------------------------------------------
// GraphActor: GCN(2 conv) + gaussian-tanh head on MI355X.
// Pipeline (fused):
//   deg/CSR build (hist -> scan -> scatter); invd = rsqrt(deg+1)
//   W01 = W_in @ W1, c01 = b_in @ W1            (tiny on-device precompute)
//   t1  = (x @ W01 + c01) * invd[row]           (skips h0 entirely)
//   h1s = relu(invd*(t1[n] + sum_adj t1[s]) + b1) * invd  (next GEMM's row scale folded)
//   t2  = h1s @ W2                              (pure GEMM)
//   h2  = relu(invd*(t2[n] + sum_adj t2[s]) + b2)   ONLY for nodes in sgen_map
//   head: mu/logstd dots, tanh, logp reduction
// ---------------------------------------------------------------------------

#define HID 128

// -------------------------- CSR build kernels ------------------------------

__global__ void k_hist(const int* __restrict__ col, int* __restrict__ deg, int E) {
    int i = blockIdx.x * blockDim.x + threadIdx.x;
    int stride = gridDim.x * blockDim.x;
    for (; i < E; i += stride) atomicAdd(&deg[col[i]], 1);
}

__global__ void k_scan1(const int* __restrict__ deg, int* __restrict__ cs, int n) {
    __shared__ int s[256];
    int t = threadIdx.x;
    int g = blockIdx.x * 256 + t;
    s[t] = (g < n) ? deg[g] : 0;
    __syncthreads();
    for (int off = 128; off; off >>= 1) {
        if (t < off) s[t] += s[t + off];
        __syncthreads();
    }
    if (t == 0) cs[blockIdx.x] = s[0];
}

__global__ void k_scan2(const int* __restrict__ cs, int* __restrict__ co, int nch) {
    __shared__ int s[512];
    int t = threadIdx.x;
    int v = (t < nch) ? cs[t] : 0;
    s[t] = v;
    __syncthreads();
    for (int off = 1; off < 512; off <<= 1) {
        int a = (t >= off) ? s[t - off] : 0;
        __syncthreads();
        s[t] += a;
        __syncthreads();
    }
    if (t < nch) co[t] = s[t] - v;   // exclusive
}

__global__ void k_scan3(const int* __restrict__ deg, const int* __restrict__ co,
                        int* __restrict__ offs, int* __restrict__ cursor,
                        float* __restrict__ invd, int n) {
    __shared__ int s[256];
    int t = threadIdx.x;
    int g = blockIdx.x * 256 + t;
    int d = (g < n) ? deg[g] : 0;
    s[t] = d;
    __syncthreads();
    for (int off = 1; off < 256; off <<= 1) {
        int a = (t >= off) ? s[t - off] : 0;
        __syncthreads();
        s[t] += a;
        __syncthreads();
    }
    if (g < n) {
        int o = co[blockIdx.x] + s[t] - d;   // exclusive prefix
        offs[g] = o;
        cursor[g] = o;
        invd[g] = rsqrtf((float)d + 1.0f);   // self-loop degree
    }
}

__global__ void k_build(const int* __restrict__ row, const int* __restrict__ col,
                        int* __restrict__ cursor, int* __restrict__ adj, int E) {
    int i = blockIdx.x * blockDim.x + threadIdx.x;
    int stride = gridDim.x * blockDim.x;
    for (; i < E; i += stride) {
        int c = col[i];
        int p = atomicAdd(&cursor[c], 1);
        adj[p] = row[i];
    }
}

// ------------------- sgen-node mark + compaction ---------------------------

__global__ void k_mark(const int* __restrict__ smap, unsigned char* __restrict__ mark, int ns) {
    int i = blockIdx.x * 256 + threadIdx.x;
    if (i < ns) mark[smap[i]] = 1;
}

__global__ void k_compact(const unsigned char* __restrict__ mark, int* __restrict__ nlist,
                          int* __restrict__ ncnt, int n) {
    int i = blockIdx.x * 256 + threadIdx.x;
    if (i < n && mark[i]) {
        int p = atomicAdd(ncnt, 1);
        nlist[p] = i;
    }
}

// --------------------- W01 = W_in @ W1, c01 = b_in @ W1 --------------------

__global__ __launch_bounds__(128) void k_w01(const float* __restrict__ W_in,
                                             const float* __restrict__ b_in,
                                             const float* __restrict__ W1,
                                             float* __restrict__ W01,
                                             float* __restrict__ c01) {
    __shared__ float rowl[HID];
    const int j = threadIdx.x;
    const int b = blockIdx.x;
    const float* src = (b < 32) ? (W_in + (size_t)b * HID) : b_in;
    rowl[j] = src[j];
    __syncthreads();
    float acc = 0.f;
#pragma unroll 8
    for (int k = 0; k < HID; ++k) acc = fmaf(rowl[k], W1[(size_t)k * HID + j], acc);
    if (b < 32) W01[(size_t)b * HID + j] = acc;
    else        c01[j] = acc;
}

// ------------------------------- GEMM --------------------------------------
// out[n x 128] = (A[n x K] @ W[K x 128] + bias) * rowscale
// Block: 256 threads; tile 128 rows x 128 cols; thread: 8x8 (split 4+4 halves).
// K in chunks of 32. LDS: Wl 16KB + hT ~17KB (pad +4 -> 4-way write conflicts).

template <int K>
__global__ __launch_bounds__(256) void gemm_k(const float* __restrict__ A,
                                              const float* __restrict__ W,
                                              const float* __restrict__ bias,
                                              const float* __restrict__ rowscale,
                                              float* __restrict__ out, int n) {
    constexpr int KC = 32;
    constexpr int NCH = K / KC;
    constexpr int K4 = KC / 4;           // float4 groups per row chunk
    __shared__ float Wl[KC][HID];
    __shared__ float hT[KC][HID + 4];

    const int tid = threadIdx.x;
    const int row0 = blockIdx.x * 128;
    const int jg = tid & 15;   // column group: 4 cols at jg*4, 4 at 64+jg*4
    const int rg = tid >> 4;   // row group:    4 rows at rg*4, 4 at 64+rg*4

    float acc[8][8];
#pragma unroll
    for (int a = 0; a < 8; ++a)
#pragma unroll
        for (int b = 0; b < 8; ++b) acc[a][b] = 0.f;

    for (int ch = 0; ch < NCH; ++ch) {
        // stage W chunk (KC x 128), linear float4 copy
        for (int i = tid; i < KC * (HID / 4); i += 256) {
            ((float4*)Wl)[i] = ((const float4*)(W + (size_t)ch * KC * HID))[i];
        }
        // stage A chunk transposed: 8 lanes cover 128B of one row -> coalesced
        for (int i = tid; i < 128 * K4; i += 256) {
            int k4 = i & (K4 - 1);
            int r = i / K4;
            int gr = row0 + r;
            float4 v = make_float4(0.f, 0.f, 0.f, 0.f);
            if (gr < n) v = *(const float4*)&A[(size_t)gr * K + ch * KC + k4 * 4];
            hT[k4 * 4 + 0][r] = v.x;
            hT[k4 * 4 + 1][r] = v.y;
            hT[k4 * 4 + 2][r] = v.z;
            hT[k4 * 4 + 3][r] = v.w;
        }
        __syncthreads();
#pragma unroll
        for (int k = 0; k < KC; ++k) {
            float4 h0 = *(const float4*)&hT[k][rg * 4];
            float4 h1 = *(const float4*)&hT[k][64 + rg * 4];
            float4 w0 = *(const float4*)&Wl[k][jg * 4];
            float4 w1 = *(const float4*)&Wl[k][64 + jg * 4];
            float hr[8] = {h0.x, h0.y, h0.z, h0.w, h1.x, h1.y, h1.z, h1.w};
            float wc[8] = {w0.x, w0.y, w0.z, w0.w, w1.x, w1.y, w1.z, w1.w};
#pragma unroll
            for (int a = 0; a < 8; ++a)
#pragma unroll
                for (int b = 0; b < 8; ++b) acc[a][b] = fmaf(hr[a], wc[b], acc[a][b]);
        }
        __syncthreads();
    }

    float bj[8];
#pragma unroll
    for (int p = 0; p < 4; ++p) {
        bj[p]     = bias ? bias[jg * 4 + p]      : 0.f;
        bj[4 + p] = bias ? bias[64 + jg * 4 + p] : 0.f;
    }
#pragma unroll
    for (int a = 0; a < 8; ++a) {
        int lr = (a < 4) ? (rg * 4 + a) : (64 + rg * 4 + a - 4);
        int gr = row0 + lr;
        if (gr >= n) continue;
        float sc = rowscale ? rowscale[gr] : 1.f;
        float* po = out + (size_t)gr * HID;
        float4 s0 = make_float4((acc[a][0] + bj[0]) * sc, (acc[a][1] + bj[1]) * sc,
                                (acc[a][2] + bj[2]) * sc, (acc[a][3] + bj[3]) * sc);
        float4 s1 = make_float4((acc[a][4] + bj[4]) * sc, (acc[a][5] + bj[5]) * sc,
                                (acc[a][6] + bj[6]) * sc, (acc[a][7] + bj[7]) * sc);
        *(float4*)&po[jg * 4] = s0;
        *(float4*)&po[64 + jg * 4] = s1;
    }
}

// --------------------------- aggregation -----------------------------------
// h_out[node] = relu(invd[node]*(t[node] + sum_{s in adj(node)} t[s]) + b) * (outscale?)
// one wave per node, float2 per lane (128 ch). Optional node-list indirection.

__global__ __launch_bounds__(256) void k_agg(const float* __restrict__ t,
                                             const int* __restrict__ offs,
                                             const int* __restrict__ deg,
                                             const int* __restrict__ adj,
                                             const float* __restrict__ invd,
                                             const float* __restrict__ bias,
                                             const float* __restrict__ outscale,
                                             const int* __restrict__ nlist,
                                             const int* __restrict__ ncnt,
                                             float* __restrict__ hout, int n) {
    int wid = threadIdx.x >> 6;
    int lane = threadIdx.x & 63;
    int idx = blockIdx.x * 4 + wid;
    int node;
    if (nlist) {
        if (idx >= *ncnt) return;
        node = nlist[idx];
    } else {
        if (idx >= n) return;
        node = idx;
    }
    const int c0 = lane * 2;
    float2 acc = *(const float2*)&t[(size_t)node * HID + c0];
    int s = offs[node];
    int cnt = deg[node];
    int j = 0;
    for (; j + 4 <= cnt; j += 4) {
        int s0 = adj[s + j + 0];
        int s1 = adj[s + j + 1];
        int s2 = adj[s + j + 2];
        int s3 = adj[s + j + 3];
        float2 v0 = *(const float2*)&t[(size_t)s0 * HID + c0];
        float2 v1 = *(const float2*)&t[(size_t)s1 * HID + c0];
        float2 v2 = *(const float2*)&t[(size_t)s2 * HID + c0];
        float2 v3 = *(const float2*)&t[(size_t)s3 * HID + c0];
        acc.x += (v0.x + v1.x) + (v2.x + v3.x);
        acc.y += (v0.y + v1.y) + (v2.y + v3.y);
    }
    for (; j < cnt; ++j) {
        int sj = adj[s + j];
        float2 v = *(const float2*)&t[(size_t)sj * HID + c0];
        acc.x += v.x;
        acc.y += v.y;
    }
    float iv = invd[node];
    float os = outscale ? outscale[node] : 1.f;
    float2 bb = *(const float2*)&bias[c0];
    float2 r;
    r.x = fmaxf(fmaf(acc.x, iv, bb.x), 0.f) * os;
    r.y = fmaxf(fmaf(acc.y, iv, bb.y), 0.f) * os;
    *(float2*)&hout[(size_t)node * HID + c0] = r;
}

// ------------------------------- head --------------------------------------

__global__ __launch_bounds__(1024) void k_head(const float* __restrict__ h,
                                               const int* __restrict__ smap,
                                               const float* __restrict__ noise,
                                               const float* __restrict__ Wmu,
                                               const float* __restrict__ bmu,
                                               const float* __restrict__ Wls,
                                               const float* __restrict__ bls,
                                               float* __restrict__ out, int ns) {
    __shared__ float part[16];
    int wid = threadIdx.x >> 6;
    int lane = threadIdx.x & 63;
    int i = blockIdx.x * 16 + wid;
    float lp = 0.f;
    if (i < ns) {
        int m = smap[i];
        float2 z = *(const float2*)&h[(size_t)m * HID + lane * 2];
        float2 wm = *(const float2*)&Wmu[lane * 2];
        float2 wl = *(const float2*)&Wls[lane * 2];
        float dmu = z.x * wm.x + z.y * wm.y;
        float dls = z.x * wl.x + z.y * wl.y;
#pragma unroll
        for (int off = 32; off; off >>= 1) {
            dmu += __shfl_xor(dmu, off);
            dls += __shfl_xor(dls, off);
        }
        float mu = dmu + bmu[0];
        float ls = fminf(fmaxf(dls + bls[0], -20.f), 2.f);
        float nz = noise[i];
        float u = fmaf(expf(ls), nz, mu);
        float a = tanhf(u);
        if (lane == 0) {
            out[i] = a;
            lp = (-0.5f * nz * nz - ls - 0.91893853320467274f)
                 - logf(1.0f - a * a + 1e-6f);
        }
    }
    if (lane == 0) part[wid] = lp;
    __syncthreads();
    if (wid == 0) {
        float v = (lane < 16) ? part[lane] : 0.f;
#pragma unroll
        for (int off = 32; off; off >>= 1) v += __shfl_xor(v, off);
        if (lane == 0) atomicAdd(&out[ns], v);
    }
}

// ------------------------------ launcher -----------------------------------

static inline size_t align256(size_t x) { return (x + 255) & ~(size_t)255; }

extern "C" void kernel_launch(void* const* d_in, const int* in_sizes, int n_in,
                              void* d_out, int out_size, void* d_ws, size_t ws_size,
                              hipStream_t stream) {
    const float* x    = (const float*)d_in[0];
    const int*   ei   = (const int*)d_in[1];
    const int*   smap = (const int*)d_in[2];
    const float* noise= (const float*)d_in[3];
    const float* W_in = (const float*)d_in[4];
    const float* b_in = (const float*)d_in[5];
    const float* W1   = (const float*)d_in[6];
    const float* b1   = (const float*)d_in[7];
    const float* W2   = (const float*)d_in[8];
    const float* b2   = (const float*)d_in[9];
    const float* Wmu  = (const float*)d_in[10];
    const float* bmu  = (const float*)d_in[11];
    const float* Wls  = (const float*)d_in[12];
    const float* bls  = (const float*)d_in[13];
    float* out = (float*)d_out;

    const int n  = in_sizes[0] / 32;   // N_NODES
    const int E  = in_sizes[1] / 2;    // N_EDGES
    const int ns = in_sizes[2];        // N_SGEN
    const int* row = ei;
    const int* col = ei + E;

    char* ws = (char*)d_ws;
    float* bufA = (float*)ws;                 ws += align256((size_t)n * HID * 4);
    float* bufB = (float*)ws;                 ws += align256((size_t)n * HID * 4);
    int* deg    = (int*)ws;                   ws += align256((size_t)n * 4);
    int* offs   = (int*)ws;                   ws += align256((size_t)n * 4);
    int* cursor = (int*)ws;                   ws += align256((size_t)n * 4);
    float* invd = (float*)ws;                 ws += align256((size_t)n * 4);
    int* cs     = (int*)ws;                   ws += align256(512 * 4);
    int* co     = (int*)ws;                   ws += align256(512 * 4);
    float* W01  = (float*)ws;                 ws += align256(32 * HID * 4);
    float* c01  = (float*)ws;                 ws += align256(HID * 4);
    unsigned char* mark = (unsigned char*)ws; ws += align256((size_t)n + 4);
    int* ncnt   = (int*)(mark + n);           // zeroed together with mark
    int* nlist  = (int*)ws;                   ws += align256((size_t)ns * 4);
    int* adj    = (int*)ws;                   ws += align256((size_t)E * 4);

    const int nchunk = (n + 255) / 256;

    // --- CSR build + invd ---
    hipMemsetAsync(deg, 0, (size_t)n * 4, stream);
    k_hist<<<2048, 256, 0, stream>>>(col, deg, E);
    k_scan1<<<nchunk, 256, 0, stream>>>(deg, cs, n);
    k_scan2<<<1, 512, 0, stream>>>(cs, co, nchunk);
    k_scan3<<<nchunk, 256, 0, stream>>>(deg, co, offs, cursor, invd, n);
    k_build<<<2048, 256, 0, stream>>>(row, col, cursor, adj, E);

    // --- sgen node set (for conv-2 dead-node elimination) ---
    hipMemsetAsync(mark, 0, (size_t)n + 4, stream);
    k_mark<<<(ns + 255) / 256, 256, 0, stream>>>(smap, mark, ns);
    k_compact<<<nchunk, 256, 0, stream>>>(mark, nlist, ncnt, n);

    // --- fused first-layer weights ---
    k_w01<<<33, 128, 0, stream>>>(W_in, b_in, W1, W01, c01);

    const int gblocks = (n + 127) / 128;
    const int ablocks = (n + 3) / 4;
    const int a2blocks = (ns + 3) / 4;   // upper bound on unique sgen nodes

    // --- network ---
    // t1 = (x @ W01 + c01) * invd[row]
    gemm_k<32><<<gblocks, 256, 0, stream>>>(x, W01, c01, invd, bufB, n);
    // h1s = relu(invd*(t1 self+nbrs) + b1) * invd   (next GEMM's row scale folded)
    k_agg<<<ablocks, 256, 0, stream>>>(bufB, offs, deg, adj, invd, b1, invd,
                                       nullptr, nullptr, bufA, n);
    // t2 = h1s @ W2
    gemm_k<128><<<gblocks, 256, 0, stream>>>(bufA, W2, nullptr, nullptr, bufB, n);
    // h2 = relu(invd*(t2 self+nbrs) + b2)  -- only for marked (sgen) nodes
    k_agg<<<a2blocks, 256, 0, stream>>>(bufB, offs, deg, adj, invd, b2, nullptr,
                                        nlist, ncnt, bufA, n);

    // --- head ---
    hipMemsetAsync(out + ns, 0, 4, stream);
    k_head<<<(ns + 15) / 16, 1024, 0, stream>>>(bufA, smap, noise, Wmu, bmu, Wls, bls, out, ns);
}

// Round 8
// 455.545 us; speedup vs baseline: 1.2621x; 1.2621x over previous
//
#include <hip/hip_runtime.h>
#include <math.h>

// ---------------------------------------------------------------------------
// GraphActor: GCN(2 conv) + gaussian-tanh head on MI355X.
//
// Round-8 = round-5/6/7 design (never benched: broker timeouts), re-audited.
//   bhist: per-block LDS 2048-bin histogram of col>>6 -> bcnt
//   bscan: exclusive scan of bcnt -> bstart/bcursor; nodeoffs[n]=E sentinel
//   binpack: per-block counting sort of edges by bucket; writes packed
//            ((col&63)<<17 | row) to per-bucket frontier runs (L2-friendly)
//   bsort: per-bucket LDS sort by node -> node-sorted adj2, nodeoffs, invd
//   W01 = W_in @ W1, c01 = b_in @ W1   (fold first two dense layers)
//   t1  = (x @ W01 + c01) * invd[row]
//   agg1: h1s = relu(invd*(sum_adj t1 + t1) + b1) * invd   (fold next scale)
//   t2  = h1s @ W2
//   agg2: h2 = relu(invd*(sum_adj t2 + t2) + b2)   only for sgen nodes
//   head: mu/logstd dots, tanh, logp reduction
// ---------------------------------------------------------------------------

#define HID 128
#define CHUNK 4096   // edges per binpack/bhist block
#define MAXB 2048    // max buckets (n <= 131072)
#define BMAX 2048    // max edges per bucket (E/nb ~ 1024, sd 32 -> safe)

// ----------------------- bucket histogram (LDS) ----------------------------

__global__ __launch_bounds__(512) void k_bhist(const int* __restrict__ col,
                                               int* __restrict__ bcnt, int E) {
    __shared__ int h[MAXB];
    const int t = threadIdx.x;
    for (int b = t; b < MAXB; b += 512) h[b] = 0;
    __syncthreads();
    const int base = blockIdx.x * CHUNK;
    const int cnt = min(CHUNK, E - base);
    for (int i = t; i < cnt; i += 512) atomicAdd(&h[col[base + i] >> 6], 1);
    __syncthreads();
    for (int b = t; b < MAXB; b += 512)
        if (h[b]) atomicAdd(&bcnt[b], h[b]);
}

__global__ void k_mark(const int* __restrict__ smap, unsigned char* __restrict__ mark, int ns) {
    int i = blockIdx.x * 256 + threadIdx.x;
    if (i < ns) mark[smap[i]] = 1;
}

__global__ void k_compact(const unsigned char* __restrict__ mark, int* __restrict__ nlist,
                          int* __restrict__ ncnt, int n) {
    int i = blockIdx.x * 256 + threadIdx.x;
    if (i < n && mark[i]) {
        int p = atomicAdd(ncnt, 1);
        nlist[p] = i;
    }
}

// ---------------- bucket starts: exclusive scan of bcnt --------------------

__global__ __launch_bounds__(1024) void k_bscan(const int* __restrict__ bcnt,
                                                int* __restrict__ bstart,
                                                int* __restrict__ bcursor,
                                                int* __restrict__ nodeoffs,
                                                int n, int nb) {
    __shared__ int sv[1024];
    const int t = threadIdx.x;
    const int a0 = bcnt[2 * t], a1 = bcnt[2 * t + 1];
    sv[t] = a0 + a1;
    __syncthreads();
    for (int off = 1; off < 1024; off <<= 1) {
        int x = (t >= off) ? sv[t - off] : 0;
        __syncthreads();
        sv[t] += x;
        __syncthreads();
    }
    const int ex = t ? sv[t - 1] : 0;   // exclusive pair prefix
    const int b0 = 2 * t, b1 = 2 * t + 1;
    if (b0 <= nb) bstart[b0] = ex;
    if (b1 <= nb) bstart[b1] = ex + a0;
    if (b0 < nb) bcursor[b0] = ex;
    if (b1 < nb) bcursor[b1] = ex + a0;
    if (t == 1023) nodeoffs[n] = sv[1023];   // == E
}

// --------------- binpack: counting-sort partition by bucket ----------------

__global__ __launch_bounds__(512) void k_binpack(const int* __restrict__ row,
                                                 const int* __restrict__ col,
                                                 int* __restrict__ bcursor,
                                                 unsigned int* __restrict__ adjp,
                                                 int E) {
    __shared__ int hist[MAXB];
    __shared__ int rs[MAXB];
    __shared__ int cur[MAXB];
    __shared__ int gb[MAXB];
    __shared__ int sv[512];
    __shared__ unsigned int sorted[CHUNK];
    __shared__ unsigned short bid[CHUNK];

    const int t = threadIdx.x;
    const int base = blockIdx.x * CHUNK;
    const int cnt = min(CHUNK, E - base);

    for (int b = t; b < MAXB; b += 512) hist[b] = 0;
    __syncthreads();
    for (int i = t; i < cnt; i += 512) atomicAdd(&hist[col[base + i] >> 6], 1);
    __syncthreads();

    const int q0 = t * 4;
    int h0 = hist[q0], h1 = hist[q0 + 1], h2 = hist[q0 + 2], h3 = hist[q0 + 3];
    sv[t] = h0 + h1 + h2 + h3;
    __syncthreads();
    for (int off = 1; off < 512; off <<= 1) {
        int x = (t >= off) ? sv[t - off] : 0;
        __syncthreads();
        sv[t] += x;
        __syncthreads();
    }
    int ex = t ? sv[t - 1] : 0;
    rs[q0] = ex;
    rs[q0 + 1] = ex + h0;
    rs[q0 + 2] = ex + h0 + h1;
    rs[q0 + 3] = ex + h0 + h1 + h2;
#pragma unroll
    for (int j = 0; j < 4; ++j) {
        int b = q0 + j;
        cur[b] = rs[b];
        gb[b] = hist[b] ? atomicAdd(&bcursor[b], hist[b]) : 0;
    }
    __syncthreads();

    for (int i = t; i < cnt; i += 512) {
        int c = col[base + i];
        unsigned int r = (unsigned int)row[base + i];
        int b = c >> 6;
        int pos = atomicAdd(&cur[b], 1);
        sorted[pos] = ((unsigned int)(c & 63) << 17) | r;
        bid[pos] = (unsigned short)b;
    }
    __syncthreads();

    for (int i = t; i < cnt; i += 512) {
        int b = bid[i];
        adjp[gb[b] + (i - rs[b])] = sorted[i];
    }
}

// ------- bsort: per-bucket node-sort -> adj2, nodeoffs, invd ---------------

__global__ __launch_bounds__(512) void k_bsort(const unsigned int* __restrict__ adjp,
                                               const int* __restrict__ bstart,
                                               int* __restrict__ adj2,
                                               int* __restrict__ nodeoffs,
                                               float* __restrict__ invd, int n) {
    __shared__ unsigned int ent[BMAX];
    __shared__ int sorted[BMAX];
    __shared__ int h64[64], off64[64], cur64[64];
    const int t = threadIdx.x;
    const int b = blockIdx.x;
    const int s = bstart[b], e = bstart[b + 1];
    const int cnt = min(e - s, BMAX);    // defensive clamp (stat. impossible)
    if (t < 64) h64[t] = 0;
    for (int i = t; i < cnt; i += 512) ent[i] = adjp[s + i];
    __syncthreads();
    for (int i = t; i < cnt; i += 512) atomicAdd(&h64[ent[i] >> 17], 1);
    __syncthreads();
    if (t < 64) off64[t] = h64[t];
    __syncthreads();
    for (int off = 1; off < 64; off <<= 1) {
        int x = 0;
        if (t < 64 && t >= off) x = off64[t - off];
        __syncthreads();
        if (t < 64) off64[t] += x;
        __syncthreads();
    }
    if (t < 64) {
        int excl = off64[t] - h64[t];
        cur64[t] = excl;
        int node = b * 64 + t;
        if (node < n) {
            nodeoffs[node] = s + excl;
            invd[node] = rsqrtf((float)h64[t] + 1.0f);
        }
    }
    __syncthreads();
    for (int i = t; i < cnt; i += 512) {
        unsigned int v = ent[i];
        int pos = atomicAdd(&cur64[v >> 17], 1);
        sorted[pos] = (int)(v & 0x1FFFFu);
    }
    __syncthreads();
    for (int i = t; i < cnt; i += 512) adj2[s + i] = sorted[i];
}

// --------------------- W01 = W_in @ W1, c01 = b_in @ W1 --------------------

__global__ __launch_bounds__(128) void k_w01(const float* __restrict__ W_in,
                                             const float* __restrict__ b_in,
                                             const float* __restrict__ W1,
                                             float* __restrict__ W01,
                                             float* __restrict__ c01) {
    __shared__ float rowl[HID];
    const int j = threadIdx.x;
    const int b = blockIdx.x;
    const float* src = (b < 32) ? (W_in + (size_t)b * HID) : b_in;
    rowl[j] = src[j];
    __syncthreads();
    float acc = 0.f;
#pragma unroll 8
    for (int k = 0; k < HID; ++k) acc = fmaf(rowl[k], W1[(size_t)k * HID + j], acc);
    if (b < 32) W01[(size_t)b * HID + j] = acc;
    else        c01[j] = acc;
}

// ------------------------------- GEMM --------------------------------------
// out[n x 128] = (A[n x K] @ W[K x 128] + bias) * rowscale
// 256 threads; tile 128x128; thread 8x8 (4+4 split halves). K chunks of 32.

template <int K>
__global__ __launch_bounds__(256) void gemm_k(const float* __restrict__ A,
                                              const float* __restrict__ W,
                                              const float* __restrict__ bias,
                                              const float* __restrict__ rowscale,
                                              float* __restrict__ out, int n) {
    constexpr int KC = 32;
    constexpr int NCH = K / KC;
    constexpr int K4 = KC / 4;
    __shared__ float Wl[KC][HID];
    __shared__ float hT[KC][HID + 4];

    const int tid = threadIdx.x;
    const int row0 = blockIdx.x * 128;
    const int jg = tid & 15;
    const int rg = tid >> 4;

    float acc[8][8];
#pragma unroll
    for (int a = 0; a < 8; ++a)
#pragma unroll
        for (int b = 0; b < 8; ++b) acc[a][b] = 0.f;

    for (int ch = 0; ch < NCH; ++ch) {
        for (int i = tid; i < KC * (HID / 4); i += 256) {
            ((float4*)Wl)[i] = ((const float4*)(W + (size_t)ch * KC * HID))[i];
        }
        for (int i = tid; i < 128 * K4; i += 256) {
            int k4 = i & (K4 - 1);
            int r = i / K4;
            int gr = row0 + r;
            float4 v = make_float4(0.f, 0.f, 0.f, 0.f);
            if (gr < n) v = *(const float4*)&A[(size_t)gr * K + ch * KC + k4 * 4];
            hT[k4 * 4 + 0][r] = v.x;
            hT[k4 * 4 + 1][r] = v.y;
            hT[k4 * 4 + 2][r] = v.z;
            hT[k4 * 4 + 3][r] = v.w;
        }
        __syncthreads();
#pragma unroll
        for (int k = 0; k < KC; ++k) {
            float4 hh0 = *(const float4*)&hT[k][rg * 4];
            float4 hh1 = *(const float4*)&hT[k][64 + rg * 4];
            float4 w0 = *(const float4*)&Wl[k][jg * 4];
            float4 w1 = *(const float4*)&Wl[k][64 + jg * 4];
            float hr[8] = {hh0.x, hh0.y, hh0.z, hh0.w, hh1.x, hh1.y, hh1.z, hh1.w};
            float wc[8] = {w0.x, w0.y, w0.z, w0.w, w1.x, w1.y, w1.z, w1.w};
#pragma unroll
            for (int a = 0; a < 8; ++a)
#pragma unroll
                for (int b = 0; b < 8; ++b) acc[a][b] = fmaf(hr[a], wc[b], acc[a][b]);
        }
        __syncthreads();
    }

    float bj[8];
#pragma unroll
    for (int p = 0; p < 4; ++p) {
        bj[p]     = bias ? bias[jg * 4 + p]      : 0.f;
        bj[4 + p] = bias ? bias[64 + jg * 4 + p] : 0.f;
    }
#pragma unroll
    for (int a = 0; a < 8; ++a) {
        int lr = (a < 4) ? (rg * 4 + a) : (64 + rg * 4 + a - 4);
        int gr = row0 + lr;
        if (gr >= n) continue;
        float sc = rowscale ? rowscale[gr] : 1.f;
        float* po = out + (size_t)gr * HID;
        float4 s0 = make_float4((acc[a][0] + bj[0]) * sc, (acc[a][1] + bj[1]) * sc,
                                (acc[a][2] + bj[2]) * sc, (acc[a][3] + bj[3]) * sc);
        float4 s1 = make_float4((acc[a][4] + bj[4]) * sc, (acc[a][5] + bj[5]) * sc,
                                (acc[a][6] + bj[6]) * sc, (acc[a][7] + bj[7]) * sc);
        *(float4*)&po[jg * 4] = s0;
        *(float4*)&po[64 + jg * 4] = s1;
    }
}

// --------------------------- aggregation -----------------------------------
// h_out[node] = relu(invd*(t[node] + sum_adj t[s]) + b) * (fold ? invd : 1)
// one wave per node, float2 per lane. Optional marked-node-list indirection.

__global__ __launch_bounds__(256) void k_agg(const float* __restrict__ t,
                                             const int* __restrict__ offs,
                                             const int* __restrict__ adj,
                                             const float* __restrict__ invd,
                                             const float* __restrict__ bias,
                                             int fold,
                                             const int* __restrict__ nlist,
                                             const int* __restrict__ ncnt,
                                             float* __restrict__ hout, int n) {
    int wid = threadIdx.x >> 6;
    int lane = threadIdx.x & 63;
    int idx = blockIdx.x * 4 + wid;
    int node;
    if (nlist) {
        if (idx >= *ncnt) return;
        node = nlist[idx];
    } else {
        if (idx >= n) return;
        node = idx;
    }
    const int c0 = lane * 2;
    float2 acc = *(const float2*)&t[(size_t)node * HID + c0];
    int j = offs[node];
    const int e = offs[node + 1];
    for (; j + 8 <= e; j += 8) {
        int s0 = adj[j + 0];
        int s1 = adj[j + 1];
        int s2 = adj[j + 2];
        int s3 = adj[j + 3];
        int s4 = adj[j + 4];
        int s5 = adj[j + 5];
        int s6 = adj[j + 6];
        int s7 = adj[j + 7];
        float2 v0 = *(const float2*)&t[(size_t)s0 * HID + c0];
        float2 v1 = *(const float2*)&t[(size_t)s1 * HID + c0];
        float2 v2 = *(const float2*)&t[(size_t)s2 * HID + c0];
        float2 v3 = *(const float2*)&t[(size_t)s3 * HID + c0];
        float2 v4 = *(const float2*)&t[(size_t)s4 * HID + c0];
        float2 v5 = *(const float2*)&t[(size_t)s5 * HID + c0];
        float2 v6 = *(const float2*)&t[(size_t)s6 * HID + c0];
        float2 v7 = *(const float2*)&t[(size_t)s7 * HID + c0];
        acc.x += ((v0.x + v1.x) + (v2.x + v3.x)) + ((v4.x + v5.x) + (v6.x + v7.x));
        acc.y += ((v0.y + v1.y) + (v2.y + v3.y)) + ((v4.y + v5.y) + (v6.y + v7.y));
    }
    for (; j < e; ++j) {
        int sj = adj[j];
        float2 v = *(const float2*)&t[(size_t)sj * HID + c0];
        acc.x += v.x;
        acc.y += v.y;
    }
    float iv = invd[node];
    float os = fold ? iv : 1.f;
    float2 bb = *(const float2*)&bias[c0];
    float2 r;
    r.x = fmaxf(fmaf(acc.x, iv, bb.x), 0.f) * os;
    r.y = fmaxf(fmaf(acc.y, iv, bb.y), 0.f) * os;
    *(float2*)&hout[(size_t)node * HID + c0] = r;
}

// ------------------------------- head --------------------------------------

__global__ __launch_bounds__(1024) void k_head(const float* __restrict__ h,
                                               const int* __restrict__ smap,
                                               const float* __restrict__ noise,
                                               const float* __restrict__ Wmu,
                                               const float* __restrict__ bmu,
                                               const float* __restrict__ Wls,
                                               const float* __restrict__ bls,
                                               float* __restrict__ out, int ns) {
    __shared__ float part[16];
    int wid = threadIdx.x >> 6;
    int lane = threadIdx.x & 63;
    int i = blockIdx.x * 16 + wid;
    float lp = 0.f;
    if (i < ns) {
        int m = smap[i];
        float2 z = *(const float2*)&h[(size_t)m * HID + lane * 2];
        float2 wm = *(const float2*)&Wmu[lane * 2];
        float2 wl = *(const float2*)&Wls[lane * 2];
        float dmu = z.x * wm.x + z.y * wm.y;
        float dls = z.x * wl.x + z.y * wl.y;
#pragma unroll
        for (int off = 32; off; off >>= 1) {
            dmu += __shfl_xor(dmu, off);
            dls += __shfl_xor(dls, off);
        }
        float mu = dmu + bmu[0];
        float ls = fminf(fmaxf(dls + bls[0], -20.f), 2.f);
        float nz = noise[i];
        float u = fmaf(expf(ls), nz, mu);
        float a = tanhf(u);
        if (lane == 0) {
            out[i] = a;
            lp = (-0.5f * nz * nz - ls - 0.91893853320467274f)
                 - logf(1.0f - a * a + 1e-6f);
        }
    }
    if (lane == 0) part[wid] = lp;
    __syncthreads();
    if (wid == 0) {
        float v = (lane < 16) ? part[lane] : 0.f;
#pragma unroll
        for (int off = 32; off; off >>= 1) v += __shfl_xor(v, off);
        if (lane == 0) atomicAdd(&out[ns], v);
    }
}

// ------------------------------ launcher -----------------------------------

static inline size_t align256(size_t x) { return (x + 255) & ~(size_t)255; }

extern "C" void kernel_launch(void* const* d_in, const int* in_sizes, int n_in,
                              void* d_out, int out_size, void* d_ws, size_t ws_size,
                              hipStream_t stream) {
    const float* x    = (const float*)d_in[0];
    const int*   ei   = (const int*)d_in[1];
    const int*   smap = (const int*)d_in[2];
    const float* noise= (const float*)d_in[3];
    const float* W_in = (const float*)d_in[4];
    const float* b_in = (const float*)d_in[5];
    const float* W1   = (const float*)d_in[6];
    const float* b1   = (const float*)d_in[7];
    const float* W2   = (const float*)d_in[8];
    const float* b2   = (const float*)d_in[9];
    const float* Wmu  = (const float*)d_in[10];
    const float* bmu  = (const float*)d_in[11];
    const float* Wls  = (const float*)d_in[12];
    const float* bls  = (const float*)d_in[13];
    float* out = (float*)d_out;

    const int n  = in_sizes[0] / 32;   // N_NODES
    const int E  = in_sizes[1] / 2;    // N_EDGES
    const int ns = in_sizes[2];        // N_SGEN
    const int* row = ei;
    const int* col = ei + E;
    const int nb = (n + 63) / 64;      // buckets (<= MAXB)

    char* ws = (char*)d_ws;
    float* bufA = (float*)ws;                 ws += align256((size_t)n * HID * 4);
    float* bufB = (float*)ws;                 ws += align256((size_t)n * HID * 4);
    int* bcnt    = (int*)ws;                  ws += align256(MAXB * 4);
    int* bstart  = (int*)ws;                  ws += align256((MAXB + 1) * 4);
    int* bcursor = (int*)ws;                  ws += align256(MAXB * 4);
    int* nodeoffs= (int*)ws;                  ws += align256(((size_t)n + 1) * 4);
    float* invd  = (float*)ws;                ws += align256((size_t)n * 4);
    unsigned char* mark = (unsigned char*)ws; ws += align256((size_t)n + 4);
    int* ncnt   = (int*)(mark + n);           // zeroed together with mark
    int* nlist  = (int*)ws;                   ws += align256((size_t)ns * 4);
    float* W01  = (float*)ws;                 ws += align256(32 * HID * 4);
    float* c01  = (float*)ws;                 ws += align256(HID * 4);
    int* adj2   = (int*)ws;                   ws += align256((size_t)E * 4);
    // adjp aliases bufB: dead before gemm<32> writes bufB (stream-ordered).
    unsigned int* adjp = (unsigned int*)bufB;

    // --- histograms + marks ---
    hipMemsetAsync(bcnt, 0, MAXB * 4, stream);
    hipMemsetAsync(mark, 0, (size_t)n + 4, stream);
    k_bhist<<<(E + CHUNK - 1) / CHUNK, 512, 0, stream>>>(col, bcnt, E);
    k_mark<<<(ns + 255) / 256, 256, 0, stream>>>(smap, mark, ns);

    // --- CSR build: scan -> partition -> bucket-local sort ---
    k_bscan<<<1, 1024, 0, stream>>>(bcnt, bstart, bcursor, nodeoffs, n, nb);
    k_w01<<<33, 128, 0, stream>>>(W_in, b_in, W1, W01, c01);
    k_binpack<<<(E + CHUNK - 1) / CHUNK, 512, 0, stream>>>(row, col, bcursor, adjp, E);
    k_bsort<<<nb, 512, 0, stream>>>(adjp, bstart, adj2, nodeoffs, invd, n);
    k_compact<<<(n + 255) / 256, 256, 0, stream>>>(mark, nlist, ncnt, n);

    const int gblocks = (n + 127) / 128;
    const int ablocks = (n + 3) / 4;
    const int a2blocks = (ns + 3) / 4;   // upper bound on unique sgen nodes

    // --- network ---
    // t1 = (x @ W01 + c01) * invd[row]       (clobbers adjp alias - OK, dead)
    gemm_k<32><<<gblocks, 256, 0, stream>>>(x, W01, c01, invd, bufB, n);
    // h1s = relu(invd*(t1 self+nbrs) + b1) * invd
    k_agg<<<ablocks, 256, 0, stream>>>(bufB, nodeoffs, adj2, invd, b1, 1,
                                       nullptr, nullptr, bufA, n);
    // t2 = h1s @ W2
    gemm_k<128><<<gblocks, 256, 0, stream>>>(bufA, W2, nullptr, nullptr, bufB, n);
    // h2 = relu(invd*(t2 self+nbrs) + b2)  -- only marked (sgen) nodes
    k_agg<<<a2blocks, 256, 0, stream>>>(bufB, nodeoffs, adj2, invd, b2, 0,
                                        nlist, ncnt, bufA, n);

    // --- head ---
    hipMemsetAsync(out + ns, 0, 4, stream);
    k_head<<<(ns + 15) / 16, 1024, 0, stream>>>(bufA, smap, noise, Wmu, bmu, Wls, bls, out, ns);
}

// Round 9
// 430.672 us; speedup vs baseline: 1.3350x; 1.0578x over previous
//
#include <hip/hip_runtime.h>
#include <math.h>

// ---------------------------------------------------------------------------
// GraphActor: GCN(2 conv) + gaussian-tanh head on MI355X.
//
// Round-9: aggregate-in-32-dim for conv-1; marked-rows-only GEMM for conv-2.
//   CSR build (bhist/bscan/binpack/bsort) as round-8 (validated, 455us total)
//   xs = x * invd                       (prep)
//   A32[n] = sum_adj xs[s] + xs[n];  S[n] = sum_adj invd[s] + invd[n]
//   h1s = relu(invd*(A32@W01) + invd*S*c01 + b1) * invd     (gemm1 epilogue)
//   G[i] = sum_adj h1s[s] + h1s[node]   for marked nodes only (aggm)
//   h2c[i] = relu(invd*(G@W2) + b2)     (gemm2, compact rows)
//   head: z = h2c[cidx[smap[i]]] -> mu/logstd, tanh, logp
// ---------------------------------------------------------------------------

#define HID 128
#define CHUNK 4096   // edges per binpack/bhist block
#define MAXB 2048    // max buckets (n <= 131072)
#define BMAX 2048    // max edges per bucket (E/nb ~ 1024, sd 32 -> safe)

// ----------------------- bucket histogram (LDS) ----------------------------

__global__ __launch_bounds__(512) void k_bhist(const int* __restrict__ col,
                                               int* __restrict__ bcnt, int E) {
    __shared__ int h[MAXB];
    const int t = threadIdx.x;
    for (int b = t; b < MAXB; b += 512) h[b] = 0;
    __syncthreads();
    const int base = blockIdx.x * CHUNK;
    const int cnt = min(CHUNK, E - base);
    for (int i = t; i < cnt; i += 512) atomicAdd(&h[col[base + i] >> 6], 1);
    __syncthreads();
    for (int b = t; b < MAXB; b += 512)
        if (h[b]) atomicAdd(&bcnt[b], h[b]);
}

__global__ void k_mark(const int* __restrict__ smap, unsigned char* __restrict__ mark, int ns) {
    int i = blockIdx.x * 256 + threadIdx.x;
    if (i < ns) mark[smap[i]] = 1;
}

__global__ void k_compact(const unsigned char* __restrict__ mark, int* __restrict__ nlist,
                          int* __restrict__ cidx, int* __restrict__ ncnt, int n) {
    int i = blockIdx.x * 256 + threadIdx.x;
    if (i < n && mark[i]) {
        int p = atomicAdd(ncnt, 1);
        nlist[p] = i;
        cidx[i] = p;
    }
}

// ---------------- bucket starts: exclusive scan of bcnt --------------------

__global__ __launch_bounds__(1024) void k_bscan(const int* __restrict__ bcnt,
                                                int* __restrict__ bstart,
                                                int* __restrict__ bcursor,
                                                int* __restrict__ nodeoffs,
                                                int n, int nb) {
    __shared__ int sv[1024];
    const int t = threadIdx.x;
    const int a0 = bcnt[2 * t], a1 = bcnt[2 * t + 1];
    sv[t] = a0 + a1;
    __syncthreads();
    for (int off = 1; off < 1024; off <<= 1) {
        int x = (t >= off) ? sv[t - off] : 0;
        __syncthreads();
        sv[t] += x;
        __syncthreads();
    }
    const int ex = t ? sv[t - 1] : 0;   // exclusive pair prefix
    const int b0 = 2 * t, b1 = 2 * t + 1;
    if (b0 <= nb) bstart[b0] = ex;
    if (b1 <= nb) bstart[b1] = ex + a0;
    if (b0 < nb) bcursor[b0] = ex;
    if (b1 < nb) bcursor[b1] = ex + a0;
    if (t == 1023) nodeoffs[n] = sv[1023];   // == E
}

// --------------- binpack: counting-sort partition by bucket ----------------

__global__ __launch_bounds__(512) void k_binpack(const int* __restrict__ row,
                                                 const int* __restrict__ col,
                                                 int* __restrict__ bcursor,
                                                 unsigned int* __restrict__ adjp,
                                                 int E) {
    __shared__ int hist[MAXB];
    __shared__ int rs[MAXB];
    __shared__ int cur[MAXB];
    __shared__ int gb[MAXB];
    __shared__ int sv[512];
    __shared__ unsigned int sorted[CHUNK];
    __shared__ unsigned short bid[CHUNK];

    const int t = threadIdx.x;
    const int base = blockIdx.x * CHUNK;
    const int cnt = min(CHUNK, E - base);

    for (int b = t; b < MAXB; b += 512) hist[b] = 0;
    __syncthreads();
    for (int i = t; i < cnt; i += 512) atomicAdd(&hist[col[base + i] >> 6], 1);
    __syncthreads();

    const int q0 = t * 4;
    int h0 = hist[q0], h1 = hist[q0 + 1], h2 = hist[q0 + 2], h3 = hist[q0 + 3];
    sv[t] = h0 + h1 + h2 + h3;
    __syncthreads();
    for (int off = 1; off < 512; off <<= 1) {
        int x = (t >= off) ? sv[t - off] : 0;
        __syncthreads();
        sv[t] += x;
        __syncthreads();
    }
    int ex = t ? sv[t - 1] : 0;
    rs[q0] = ex;
    rs[q0 + 1] = ex + h0;
    rs[q0 + 2] = ex + h0 + h1;
    rs[q0 + 3] = ex + h0 + h1 + h2;
#pragma unroll
    for (int j = 0; j < 4; ++j) {
        int b = q0 + j;
        cur[b] = rs[b];
        gb[b] = hist[b] ? atomicAdd(&bcursor[b], hist[b]) : 0;
    }
    __syncthreads();

    for (int i = t; i < cnt; i += 512) {
        int c = col[base + i];
        unsigned int r = (unsigned int)row[base + i];
        int b = c >> 6;
        int pos = atomicAdd(&cur[b], 1);
        sorted[pos] = ((unsigned int)(c & 63) << 17) | r;
        bid[pos] = (unsigned short)b;
    }
    __syncthreads();

    for (int i = t; i < cnt; i += 512) {
        int b = bid[i];
        adjp[gb[b] + (i - rs[b])] = sorted[i];
    }
}

// ------- bsort: per-bucket node-sort -> adj2, nodeoffs, invd ---------------

__global__ __launch_bounds__(512) void k_bsort(const unsigned int* __restrict__ adjp,
                                               const int* __restrict__ bstart,
                                               int* __restrict__ adj2,
                                               int* __restrict__ nodeoffs,
                                               float* __restrict__ invd, int n) {
    __shared__ unsigned int ent[BMAX];
    __shared__ int sorted[BMAX];
    __shared__ int h64[64], off64[64], cur64[64];
    const int t = threadIdx.x;
    const int b = blockIdx.x;
    const int s = bstart[b], e = bstart[b + 1];
    const int cnt = min(e - s, BMAX);    // defensive clamp (stat. impossible)
    if (t < 64) h64[t] = 0;
    for (int i = t; i < cnt; i += 512) ent[i] = adjp[s + i];
    __syncthreads();
    for (int i = t; i < cnt; i += 512) atomicAdd(&h64[ent[i] >> 17], 1);
    __syncthreads();
    if (t < 64) off64[t] = h64[t];
    __syncthreads();
    for (int off = 1; off < 64; off <<= 1) {
        int x = 0;
        if (t < 64 && t >= off) x = off64[t - off];
        __syncthreads();
        if (t < 64) off64[t] += x;
        __syncthreads();
    }
    if (t < 64) {
        int excl = off64[t] - h64[t];
        cur64[t] = excl;
        int node = b * 64 + t;
        if (node < n) {
            nodeoffs[node] = s + excl;
            invd[node] = rsqrtf((float)h64[t] + 1.0f);
        }
    }
    __syncthreads();
    for (int i = t; i < cnt; i += 512) {
        unsigned int v = ent[i];
        int pos = atomicAdd(&cur64[v >> 17], 1);
        sorted[pos] = (int)(v & 0x1FFFFu);
    }
    __syncthreads();
    for (int i = t; i < cnt; i += 512) adj2[s + i] = sorted[i];
}

// --------------------- W01 = W_in @ W1, c01 = b_in @ W1 --------------------

__global__ __launch_bounds__(128) void k_w01(const float* __restrict__ W_in,
                                             const float* __restrict__ b_in,
                                             const float* __restrict__ W1,
                                             float* __restrict__ W01,
                                             float* __restrict__ c01) {
    __shared__ float rowl[HID];
    const int j = threadIdx.x;
    const int b = blockIdx.x;
    const float* src = (b < 32) ? (W_in + (size_t)b * HID) : b_in;
    rowl[j] = src[j];
    __syncthreads();
    float acc = 0.f;
#pragma unroll 8
    for (int k = 0; k < HID; ++k) acc = fmaf(rowl[k], W1[(size_t)k * HID + j], acc);
    if (b < 32) W01[(size_t)b * HID + j] = acc;
    else        c01[j] = acc;
}

// ----------------------- xs = x * invd (prep) ------------------------------

__global__ void k_prep(const float* __restrict__ x, const float* __restrict__ invd,
                       float* __restrict__ xs, int n) {
    int i = blockIdx.x * 256 + threadIdx.x;   // one float4 (8 per row)
    if (i < n * 8) {
        int node = i >> 3;
        float4 v = ((const float4*)x)[i];
        float iv = invd[node];
        v.x *= iv; v.y *= iv; v.z *= iv; v.w *= iv;
        ((float4*)xs)[i] = v;
    }
}

// ------------- conv-1 aggregation in 32-dim input space --------------------
// A32[n] = sum_adj xs[s] + xs[n];  qv[n] = invd[n]*(sum_adj invd[s] + invd[n])
// one wave per node; 4 lane-groups x 16 lanes (float2 channels).

__global__ __launch_bounds__(256) void k_agg32(const float* __restrict__ xs,
                                               const float* __restrict__ invd,
                                               const int* __restrict__ offs,
                                               const int* __restrict__ adj,
                                               float* __restrict__ A32,
                                               float* __restrict__ qv, int n) {
    int wid = threadIdx.x >> 6;
    int lane = threadIdx.x & 63;
    int node = blockIdx.x * 4 + wid;
    if (node >= n) return;
    const int g = lane >> 4;        // neighbor sub-group
    const int c0 = (lane & 15) * 2; // channel pair
    float2 acc = make_float2(0.f, 0.f);
    float sacc = 0.f;
    const int s = offs[node], e = offs[node + 1];
    for (int j = s + g; j < e; j += 4) {
        int sj = adj[j];
        float2 v = *(const float2*)&xs[(size_t)sj * 32 + c0];
        acc.x += v.x;
        acc.y += v.y;
        sacc += invd[sj];
    }
    if (g == 0) {   // self term, counted once
        float2 v = *(const float2*)&xs[(size_t)node * 32 + c0];
        acc.x += v.x;
        acc.y += v.y;
    }
    acc.x += __shfl_xor(acc.x, 16);
    acc.y += __shfl_xor(acc.y, 16);
    acc.x += __shfl_xor(acc.x, 32);
    acc.y += __shfl_xor(acc.y, 32);
    sacc  += __shfl_xor(sacc, 16);
    sacc  += __shfl_xor(sacc, 32);
    float iv = invd[node];
    if (lane < 16) *(float2*)&A32[(size_t)node * 32 + c0] = acc;
    if (lane == 0) qv[node] = iv * (sacc + iv);
}

// ------------- gemm1: h1s = relu(p*(A32@W01) + q*c01 + b1) * p -------------
// 256 threads; tile 128x128; thread 8x8. K=32 single chunk.

__global__ __launch_bounds__(256) void gemm1(const float* __restrict__ A,
                                             const float* __restrict__ W,
                                             const float* __restrict__ c01,
                                             const float* __restrict__ b1,
                                             const float* __restrict__ invd,
                                             const float* __restrict__ qv,
                                             float* __restrict__ out, int n) {
    constexpr int KC = 32;
    constexpr int K4 = KC / 4;
    __shared__ float Wl[KC][HID];
    __shared__ float hT[KC][HID + 4];

    const int tid = threadIdx.x;
    const int row0 = blockIdx.x * 128;
    const int jg = tid & 15;
    const int rg = tid >> 4;

    float acc[8][8];
#pragma unroll
    for (int a = 0; a < 8; ++a)
#pragma unroll
        for (int b = 0; b < 8; ++b) acc[a][b] = 0.f;

    for (int i = tid; i < KC * (HID / 4); i += 256)
        ((float4*)Wl)[i] = ((const float4*)W)[i];
    for (int i = tid; i < 128 * K4; i += 256) {
        int k4 = i & (K4 - 1);
        int r = i / K4;
        int gr = row0 + r;
        float4 v = make_float4(0.f, 0.f, 0.f, 0.f);
        if (gr < n) v = *(const float4*)&A[(size_t)gr * KC + k4 * 4];
        hT[k4 * 4 + 0][r] = v.x;
        hT[k4 * 4 + 1][r] = v.y;
        hT[k4 * 4 + 2][r] = v.z;
        hT[k4 * 4 + 3][r] = v.w;
    }
    __syncthreads();
#pragma unroll
    for (int k = 0; k < KC; ++k) {
        float4 hh0 = *(const float4*)&hT[k][rg * 4];
        float4 hh1 = *(const float4*)&hT[k][64 + rg * 4];
        float4 w0 = *(const float4*)&Wl[k][jg * 4];
        float4 w1 = *(const float4*)&Wl[k][64 + jg * 4];
        float hr[8] = {hh0.x, hh0.y, hh0.z, hh0.w, hh1.x, hh1.y, hh1.z, hh1.w};
        float wc[8] = {w0.x, w0.y, w0.z, w0.w, w1.x, w1.y, w1.z, w1.w};
#pragma unroll
        for (int a = 0; a < 8; ++a)
#pragma unroll
            for (int b = 0; b < 8; ++b) acc[a][b] = fmaf(hr[a], wc[b], acc[a][b]);
    }

    float cj[8], bj[8];
#pragma unroll
    for (int p = 0; p < 4; ++p) {
        cj[p]     = c01[jg * 4 + p];      bj[p]     = b1[jg * 4 + p];
        cj[4 + p] = c01[64 + jg * 4 + p]; bj[4 + p] = b1[64 + jg * 4 + p];
    }
#pragma unroll
    for (int a = 0; a < 8; ++a) {
        int lr = (a < 4) ? (rg * 4 + a) : (64 + rg * 4 + a - 4);
        int gr = row0 + lr;
        if (gr >= n) continue;
        float p = invd[gr];
        float q = qv[gr];
        float* po = out + (size_t)gr * HID;
        float4 s0, s1;
        s0.x = fmaxf(fmaf(acc[a][0], p, fmaf(q, cj[0], bj[0])), 0.f) * p;
        s0.y = fmaxf(fmaf(acc[a][1], p, fmaf(q, cj[1], bj[1])), 0.f) * p;
        s0.z = fmaxf(fmaf(acc[a][2], p, fmaf(q, cj[2], bj[2])), 0.f) * p;
        s0.w = fmaxf(fmaf(acc[a][3], p, fmaf(q, cj[3], bj[3])), 0.f) * p;
        s1.x = fmaxf(fmaf(acc[a][4], p, fmaf(q, cj[4], bj[4])), 0.f) * p;
        s1.y = fmaxf(fmaf(acc[a][5], p, fmaf(q, cj[5], bj[5])), 0.f) * p;
        s1.z = fmaxf(fmaf(acc[a][6], p, fmaf(q, cj[6], bj[6])), 0.f) * p;
        s1.w = fmaxf(fmaf(acc[a][7], p, fmaf(q, cj[7], bj[7])), 0.f) * p;
        *(float4*)&po[jg * 4] = s0;
        *(float4*)&po[64 + jg * 4] = s1;
    }
}

// ---------- conv-2 aggregation (marked nodes only, compact output) ---------
// G[i] = sum_adj h1s[s] + h1s[nlist[i]]

__global__ __launch_bounds__(256) void k_aggm(const float* __restrict__ t,
                                              const int* __restrict__ offs,
                                              const int* __restrict__ adj,
                                              const int* __restrict__ nlist,
                                              const int* __restrict__ ncnt,
                                              float* __restrict__ G) {
    int wid = threadIdx.x >> 6;
    int lane = threadIdx.x & 63;
    int idx = blockIdx.x * 4 + wid;
    if (idx >= *ncnt) return;
    int node = nlist[idx];
    const int c0 = lane * 2;
    float2 acc = *(const float2*)&t[(size_t)node * HID + c0];
    int j = offs[node];
    const int e = offs[node + 1];
    for (; j + 4 <= e; j += 4) {
        int s0 = adj[j + 0];
        int s1 = adj[j + 1];
        int s2 = adj[j + 2];
        int s3 = adj[j + 3];
        float2 v0 = *(const float2*)&t[(size_t)s0 * HID + c0];
        float2 v1 = *(const float2*)&t[(size_t)s1 * HID + c0];
        float2 v2 = *(const float2*)&t[(size_t)s2 * HID + c0];
        float2 v3 = *(const float2*)&t[(size_t)s3 * HID + c0];
        acc.x += (v0.x + v1.x) + (v2.x + v3.x);
        acc.y += (v0.y + v1.y) + (v2.y + v3.y);
    }
    for (; j < e; ++j) {
        int sj = adj[j];
        float2 v = *(const float2*)&t[(size_t)sj * HID + c0];
        acc.x += v.x;
        acc.y += v.y;
    }
    *(float2*)&G[(size_t)idx * HID + c0] = acc;
}

// ------------- gemm2: h2c = relu(p*(G@W2) + b2), compact rows --------------

__global__ __launch_bounds__(256) void gemm2(const float* __restrict__ G,
                                             const float* __restrict__ W,
                                             const float* __restrict__ b2,
                                             const float* __restrict__ invd,
                                             const int* __restrict__ nlist,
                                             const int* __restrict__ ncnt,
                                             float* __restrict__ out) {
    constexpr int KC = 32;
    constexpr int NCH = HID / KC;
    constexpr int K4 = KC / 4;
    __shared__ float Wl[KC][HID];
    __shared__ float hT[KC][HID + 4];

    const int m = *ncnt;
    const int tid = threadIdx.x;
    const int row0 = blockIdx.x * 128;
    const int jg = tid & 15;
    const int rg = tid >> 4;

    float acc[8][8];
#pragma unroll
    for (int a = 0; a < 8; ++a)
#pragma unroll
        for (int b = 0; b < 8; ++b) acc[a][b] = 0.f;

    for (int ch = 0; ch < NCH; ++ch) {
        for (int i = tid; i < KC * (HID / 4); i += 256)
            ((float4*)Wl)[i] = ((const float4*)(W + (size_t)ch * KC * HID))[i];
        for (int i = tid; i < 128 * K4; i += 256) {
            int k4 = i & (K4 - 1);
            int r = i / K4;
            int gr = row0 + r;
            float4 v = make_float4(0.f, 0.f, 0.f, 0.f);
            if (gr < m) v = *(const float4*)&G[(size_t)gr * HID + ch * KC + k4 * 4];
            hT[k4 * 4 + 0][r] = v.x;
            hT[k4 * 4 + 1][r] = v.y;
            hT[k4 * 4 + 2][r] = v.z;
            hT[k4 * 4 + 3][r] = v.w;
        }
        __syncthreads();
#pragma unroll
        for (int k = 0; k < KC; ++k) {
            float4 hh0 = *(const float4*)&hT[k][rg * 4];
            float4 hh1 = *(const float4*)&hT[k][64 + rg * 4];
            float4 w0 = *(const float4*)&Wl[k][jg * 4];
            float4 w1 = *(const float4*)&Wl[k][64 + jg * 4];
            float hr[8] = {hh0.x, hh0.y, hh0.z, hh0.w, hh1.x, hh1.y, hh1.z, hh1.w};
            float wc[8] = {w0.x, w0.y, w0.z, w0.w, w1.x, w1.y, w1.z, w1.w};
#pragma unroll
            for (int a = 0; a < 8; ++a)
#pragma unroll
                for (int b = 0; b < 8; ++b) acc[a][b] = fmaf(hr[a], wc[b], acc[a][b]);
        }
        __syncthreads();
    }

    float bj[8];
#pragma unroll
    for (int p = 0; p < 4; ++p) {
        bj[p]     = b2[jg * 4 + p];
        bj[4 + p] = b2[64 + jg * 4 + p];
    }
#pragma unroll
    for (int a = 0; a < 8; ++a) {
        int lr = (a < 4) ? (rg * 4 + a) : (64 + rg * 4 + a - 4);
        int gr = row0 + lr;
        if (gr >= m) continue;
        float p = invd[nlist[gr]];
        float* po = out + (size_t)gr * HID;
        float4 s0 = make_float4(fmaxf(fmaf(acc[a][0], p, bj[0]), 0.f),
                                fmaxf(fmaf(acc[a][1], p, bj[1]), 0.f),
                                fmaxf(fmaf(acc[a][2], p, bj[2]), 0.f),
                                fmaxf(fmaf(acc[a][3], p, bj[3]), 0.f));
        float4 s1 = make_float4(fmaxf(fmaf(acc[a][4], p, bj[4]), 0.f),
                                fmaxf(fmaf(acc[a][5], p, bj[5]), 0.f),
                                fmaxf(fmaf(acc[a][6], p, bj[6]), 0.f),
                                fmaxf(fmaf(acc[a][7], p, bj[7]), 0.f));
        *(float4*)&po[jg * 4] = s0;
        *(float4*)&po[64 + jg * 4] = s1;
    }
}

// ------------------------------- head --------------------------------------

__global__ __launch_bounds__(1024) void k_head(const float* __restrict__ h2c,
                                               const int* __restrict__ cidx,
                                               const int* __restrict__ smap,
                                               const float* __restrict__ noise,
                                               const float* __restrict__ Wmu,
                                               const float* __restrict__ bmu,
                                               const float* __restrict__ Wls,
                                               const float* __restrict__ bls,
                                               float* __restrict__ out, int ns) {
    __shared__ float part[16];
    int wid = threadIdx.x >> 6;
    int lane = threadIdx.x & 63;
    int i = blockIdx.x * 16 + wid;
    float lp = 0.f;
    if (i < ns) {
        int m = cidx[smap[i]];
        float2 z = *(const float2*)&h2c[(size_t)m * HID + lane * 2];
        float2 wm = *(const float2*)&Wmu[lane * 2];
        float2 wl = *(const float2*)&Wls[lane * 2];
        float dmu = z.x * wm.x + z.y * wm.y;
        float dls = z.x * wl.x + z.y * wl.y;
#pragma unroll
        for (int off = 32; off; off >>= 1) {
            dmu += __shfl_xor(dmu, off);
            dls += __shfl_xor(dls, off);
        }
        float mu = dmu + bmu[0];
        float ls = fminf(fmaxf(dls + bls[0], -20.f), 2.f);
        float nz = noise[i];
        float u = fmaf(expf(ls), nz, mu);
        float a = tanhf(u);
        if (lane == 0) {
            out[i] = a;
            lp = (-0.5f * nz * nz - ls - 0.91893853320467274f)
                 - logf(1.0f - a * a + 1e-6f);
        }
    }
    if (lane == 0) part[wid] = lp;
    __syncthreads();
    if (wid == 0) {
        float v = (lane < 16) ? part[lane] : 0.f;
#pragma unroll
        for (int off = 32; off; off >>= 1) v += __shfl_xor(v, off);
        if (lane == 0) atomicAdd(&out[ns], v);
    }
}

// ------------------------------ launcher -----------------------------------

static inline size_t align256(size_t x) { return (x + 255) & ~(size_t)255; }

extern "C" void kernel_launch(void* const* d_in, const int* in_sizes, int n_in,
                              void* d_out, int out_size, void* d_ws, size_t ws_size,
                              hipStream_t stream) {
    const float* x    = (const float*)d_in[0];
    const int*   ei   = (const int*)d_in[1];
    const int*   smap = (const int*)d_in[2];
    const float* noise= (const float*)d_in[3];
    const float* W_in = (const float*)d_in[4];
    const float* b_in = (const float*)d_in[5];
    const float* W1   = (const float*)d_in[6];
    const float* b1   = (const float*)d_in[7];
    const float* W2   = (const float*)d_in[8];
    const float* b2   = (const float*)d_in[9];
    const float* Wmu  = (const float*)d_in[10];
    const float* bmu  = (const float*)d_in[11];
    const float* Wls  = (const float*)d_in[12];
    const float* bls  = (const float*)d_in[13];
    float* out = (float*)d_out;

    const int n  = in_sizes[0] / 32;   // N_NODES
    const int E  = in_sizes[1] / 2;    // N_EDGES
    const int ns = in_sizes[2];        // N_SGEN
    const int* row = ei;
    const int* col = ei + E;
    const int nb = (n + 63) / 64;      // buckets (<= MAXB)

    char* ws = (char*)d_ws;
    float* h1s  = (float*)ws;                 ws += align256((size_t)n * HID * 4);   // bufA
    float* xs   = (float*)ws;                 ws += align256((size_t)n * 32 * 4);
    float* A32  = (float*)ws;                 ws += align256((size_t)n * 32 * 4);
    float* qv   = (float*)ws;                 ws += align256((size_t)n * 4);
    float* G    = (float*)ws;                 ws += align256((size_t)ns * HID * 4);
    float* h2c  = (float*)ws;                 ws += align256((size_t)ns * HID * 4);
    int* bcnt    = (int*)ws;                  ws += align256(MAXB * 4);
    int* bstart  = (int*)ws;                  ws += align256((MAXB + 1) * 4);
    int* bcursor = (int*)ws;                  ws += align256(MAXB * 4);
    int* nodeoffs= (int*)ws;                  ws += align256(((size_t)n + 1) * 4);
    float* invd  = (float*)ws;                ws += align256((size_t)n * 4);
    unsigned char* mark = (unsigned char*)ws; ws += align256((size_t)n + 4);
    int* ncnt   = (int*)(mark + n);           // zeroed together with mark
    int* nlist  = (int*)ws;                   ws += align256((size_t)ns * 4);
    int* cidx   = (int*)ws;                   ws += align256((size_t)n * 4);
    float* W01  = (float*)ws;                 ws += align256(32 * HID * 4);
    float* c01  = (float*)ws;                 ws += align256(HID * 4);
    int* adj2   = (int*)ws;                   ws += align256((size_t)E * 4);
    // adjp aliases h1s head: dead before gemm1 writes h1s (stream-ordered).
    unsigned int* adjp = (unsigned int*)h1s;

    // --- histograms + marks ---
    hipMemsetAsync(bcnt, 0, MAXB * 4, stream);
    hipMemsetAsync(mark, 0, (size_t)n + 4, stream);
    k_bhist<<<(E + CHUNK - 1) / CHUNK, 512, 0, stream>>>(col, bcnt, E);
    k_mark<<<(ns + 255) / 256, 256, 0, stream>>>(smap, mark, ns);

    // --- CSR build: scan -> partition -> bucket-local sort ---
    k_bscan<<<1, 1024, 0, stream>>>(bcnt, bstart, bcursor, nodeoffs, n, nb);
    k_w01<<<33, 128, 0, stream>>>(W_in, b_in, W1, W01, c01);
    k_binpack<<<(E + CHUNK - 1) / CHUNK, 512, 0, stream>>>(row, col, bcursor, adjp, E);
    k_bsort<<<nb, 512, 0, stream>>>(adjp, bstart, adj2, nodeoffs, invd, n);
    k_compact<<<(n + 255) / 256, 256, 0, stream>>>(mark, nlist, cidx, ncnt, n);

    const int gblocks = (n + 127) / 128;
    const int ablocks = (n + 3) / 4;
    const int mblocks = (ns + 3) / 4;      // marked-node upper bound
    const int g2blocks = (ns + 127) / 128;

    // --- network ---
    // conv-1 in 32-dim space
    k_prep<<<(n * 8 + 255) / 256, 256, 0, stream>>>(x, invd, xs, n);
    k_agg32<<<ablocks, 256, 0, stream>>>(xs, invd, nodeoffs, adj2, A32, qv, n);
    gemm1<<<gblocks, 256, 0, stream>>>(A32, W01, c01, b1, invd, qv, h1s, n);
    // conv-2: gather first, GEMM on compact marked rows only
    k_aggm<<<mblocks, 256, 0, stream>>>(h1s, nodeoffs, adj2, nlist, ncnt, G);
    gemm2<<<g2blocks, 256, 0, stream>>>(G, W2, b2, invd, nlist, ncnt, h2c);

    // --- head ---
    hipMemsetAsync(out + ns, 0, 4, stream);
    k_head<<<(ns + 15) / 16, 1024, 0, stream>>>(h2c, cidx, smap, noise,
                                                Wmu, bmu, Wls, bls, out, ns);
}

// Round 10
// 353.937 us; speedup vs baseline: 1.6245x; 1.2168x over previous
//
#include <hip/hip_runtime.h>
#include <math.h>

// ---------------------------------------------------------------------------
// GraphActor: GCN(2 conv) + gaussian-tanh head on MI355X.
//
// Round-10: low-VGPR GEMMs (r9's gemm1 spilled: 256 VGPR, 9.7% occ, 143us).
//   CSR build (bhist/bscan/binpack/bsort) as round-8/9 (validated)
//   agg32: A32[n] = sum_adj x[s]*invd[s] + x[n]*invd[n]; qv = invd*(S+invd)
//          (k_prep folded: reads x directly, scales in-flight)
//   gemm1: h1s = relu(p*(A32@W01) + qv*c01 + b1) * p   -- broadcast design,
//          acc in 4 VGPRs, W01+A-tile in LDS, grid-stride
//   aggm:  G[i] = sum_adj h1s[s] + h1s[node]  (marked nodes only)
//   gemm2: h2c = relu(p*(G@W2) + b2)          -- 64x128 tile, 4x8 thread tile
//   head:  z = h2c[cidx[smap[i]]] -> mu/logstd, tanh, logp
// ---------------------------------------------------------------------------

#define HID 128
#define CHUNK 4096   // edges per binpack/bhist block
#define MAXB 2048    // max buckets (n <= 131072)
#define BMAX 2048    // max edges per bucket (E/nb ~ 1024, sd 32 -> safe)

// ----------------------- bucket histogram (LDS) ----------------------------

__global__ __launch_bounds__(512) void k_bhist(const int* __restrict__ col,
                                               int* __restrict__ bcnt, int E) {
    __shared__ int h[MAXB];
    const int t = threadIdx.x;
    for (int b = t; b < MAXB; b += 512) h[b] = 0;
    __syncthreads();
    const int base = blockIdx.x * CHUNK;
    const int cnt = min(CHUNK, E - base);
    for (int i = t; i < cnt; i += 512) atomicAdd(&h[col[base + i] >> 6], 1);
    __syncthreads();
    for (int b = t; b < MAXB; b += 512)
        if (h[b]) atomicAdd(&bcnt[b], h[b]);
}

__global__ void k_mark(const int* __restrict__ smap, unsigned char* __restrict__ mark, int ns) {
    int i = blockIdx.x * 256 + threadIdx.x;
    if (i < ns) mark[smap[i]] = 1;
}

__global__ void k_compact(const unsigned char* __restrict__ mark, int* __restrict__ nlist,
                          int* __restrict__ cidx, int* __restrict__ ncnt, int n) {
    int i = blockIdx.x * 256 + threadIdx.x;
    if (i < n && mark[i]) {
        int p = atomicAdd(ncnt, 1);
        nlist[p] = i;
        cidx[i] = p;
    }
}

// ---------------- bucket starts: exclusive scan of bcnt --------------------

__global__ __launch_bounds__(1024) void k_bscan(const int* __restrict__ bcnt,
                                                int* __restrict__ bstart,
                                                int* __restrict__ bcursor,
                                                int* __restrict__ nodeoffs,
                                                int n, int nb) {
    __shared__ int sv[1024];
    const int t = threadIdx.x;
    const int a0 = bcnt[2 * t], a1 = bcnt[2 * t + 1];
    sv[t] = a0 + a1;
    __syncthreads();
    for (int off = 1; off < 1024; off <<= 1) {
        int x = (t >= off) ? sv[t - off] : 0;
        __syncthreads();
        sv[t] += x;
        __syncthreads();
    }
    const int ex = t ? sv[t - 1] : 0;   // exclusive pair prefix
    const int b0 = 2 * t, b1 = 2 * t + 1;
    if (b0 <= nb) bstart[b0] = ex;
    if (b1 <= nb) bstart[b1] = ex + a0;
    if (b0 < nb) bcursor[b0] = ex;
    if (b1 < nb) bcursor[b1] = ex + a0;
    if (t == 1023) nodeoffs[n] = sv[1023];   // == E
}

// --------------- binpack: counting-sort partition by bucket ----------------

__global__ __launch_bounds__(512) void k_binpack(const int* __restrict__ row,
                                                 const int* __restrict__ col,
                                                 int* __restrict__ bcursor,
                                                 unsigned int* __restrict__ adjp,
                                                 int E) {
    __shared__ int hist[MAXB];
    __shared__ int rs[MAXB];
    __shared__ int cur[MAXB];
    __shared__ int gb[MAXB];
    __shared__ int sv[512];
    __shared__ unsigned int sorted[CHUNK];
    __shared__ unsigned short bid[CHUNK];

    const int t = threadIdx.x;
    const int base = blockIdx.x * CHUNK;
    const int cnt = min(CHUNK, E - base);

    for (int b = t; b < MAXB; b += 512) hist[b] = 0;
    __syncthreads();
    for (int i = t; i < cnt; i += 512) atomicAdd(&hist[col[base + i] >> 6], 1);
    __syncthreads();

    const int q0 = t * 4;
    int h0 = hist[q0], h1 = hist[q0 + 1], h2 = hist[q0 + 2], h3 = hist[q0 + 3];
    sv[t] = h0 + h1 + h2 + h3;
    __syncthreads();
    for (int off = 1; off < 512; off <<= 1) {
        int x = (t >= off) ? sv[t - off] : 0;
        __syncthreads();
        sv[t] += x;
        __syncthreads();
    }
    int ex = t ? sv[t - 1] : 0;
    rs[q0] = ex;
    rs[q0 + 1] = ex + h0;
    rs[q0 + 2] = ex + h0 + h1;
    rs[q0 + 3] = ex + h0 + h1 + h2;
#pragma unroll
    for (int j = 0; j < 4; ++j) {
        int b = q0 + j;
        cur[b] = rs[b];
        gb[b] = hist[b] ? atomicAdd(&bcursor[b], hist[b]) : 0;
    }
    __syncthreads();

    for (int i = t; i < cnt; i += 512) {
        int c = col[base + i];
        unsigned int r = (unsigned int)row[base + i];
        int b = c >> 6;
        int pos = atomicAdd(&cur[b], 1);
        sorted[pos] = ((unsigned int)(c & 63) << 17) | r;
        bid[pos] = (unsigned short)b;
    }
    __syncthreads();

    for (int i = t; i < cnt; i += 512) {
        int b = bid[i];
        adjp[gb[b] + (i - rs[b])] = sorted[i];
    }
}

// ------- bsort: per-bucket node-sort -> adj2, nodeoffs, invd ---------------

__global__ __launch_bounds__(512) void k_bsort(const unsigned int* __restrict__ adjp,
                                               const int* __restrict__ bstart,
                                               int* __restrict__ adj2,
                                               int* __restrict__ nodeoffs,
                                               float* __restrict__ invd, int n) {
    __shared__ unsigned int ent[BMAX];
    __shared__ int sorted[BMAX];
    __shared__ int h64[64], off64[64], cur64[64];
    const int t = threadIdx.x;
    const int b = blockIdx.x;
    const int s = bstart[b], e = bstart[b + 1];
    const int cnt = min(e - s, BMAX);    // defensive clamp (stat. impossible)
    if (t < 64) h64[t] = 0;
    for (int i = t; i < cnt; i += 512) ent[i] = adjp[s + i];
    __syncthreads();
    for (int i = t; i < cnt; i += 512) atomicAdd(&h64[ent[i] >> 17], 1);
    __syncthreads();
    if (t < 64) off64[t] = h64[t];
    __syncthreads();
    for (int off = 1; off < 64; off <<= 1) {
        int x = 0;
        if (t < 64 && t >= off) x = off64[t - off];
        __syncthreads();
        if (t < 64) off64[t] += x;
        __syncthreads();
    }
    if (t < 64) {
        int excl = off64[t] - h64[t];
        cur64[t] = excl;
        int node = b * 64 + t;
        if (node < n) {
            nodeoffs[node] = s + excl;
            invd[node] = rsqrtf((float)h64[t] + 1.0f);
        }
    }
    __syncthreads();
    for (int i = t; i < cnt; i += 512) {
        unsigned int v = ent[i];
        int pos = atomicAdd(&cur64[v >> 17], 1);
        sorted[pos] = (int)(v & 0x1FFFFu);
    }
    __syncthreads();
    for (int i = t; i < cnt; i += 512) adj2[s + i] = sorted[i];
}

// --------------------- W01 = W_in @ W1, c01 = b_in @ W1 --------------------

__global__ __launch_bounds__(128) void k_w01(const float* __restrict__ W_in,
                                             const float* __restrict__ b_in,
                                             const float* __restrict__ W1,
                                             float* __restrict__ W01,
                                             float* __restrict__ c01) {
    __shared__ float rowl[HID];
    const int j = threadIdx.x;
    const int b = blockIdx.x;
    const float* src = (b < 32) ? (W_in + (size_t)b * HID) : b_in;
    rowl[j] = src[j];
    __syncthreads();
    float acc = 0.f;
#pragma unroll 8
    for (int k = 0; k < HID; ++k) acc = fmaf(rowl[k], W1[(size_t)k * HID + j], acc);
    if (b < 32) W01[(size_t)b * HID + j] = acc;
    else        c01[j] = acc;
}

// ------------- conv-1 aggregation in 32-dim input space --------------------
// A32[n] = sum_adj x[s]*invd[s] + x[n]*invd[n]
// qv[n]  = invd[n]*(sum_adj invd[s] + invd[n])
// one wave per node; 4 lane-groups x 16 lanes (float2 channels).

__global__ __launch_bounds__(256) void k_agg32(const float* __restrict__ x,
                                               const float* __restrict__ invd,
                                               const int* __restrict__ offs,
                                               const int* __restrict__ adj,
                                               float* __restrict__ A32,
                                               float* __restrict__ qv, int n) {
    int wid = threadIdx.x >> 6;
    int lane = threadIdx.x & 63;
    int node = blockIdx.x * 4 + wid;
    if (node >= n) return;
    const int g = lane >> 4;        // neighbor sub-group
    const int c0 = (lane & 15) * 2; // channel pair
    float2 acc = make_float2(0.f, 0.f);
    float sacc = 0.f;
    const int s = offs[node], e = offs[node + 1];
    for (int j = s + g; j < e; j += 4) {
        int sj = adj[j];
        float ivs = invd[sj];
        float2 v = *(const float2*)&x[(size_t)sj * 32 + c0];
        acc.x = fmaf(v.x, ivs, acc.x);
        acc.y = fmaf(v.y, ivs, acc.y);
        sacc += ivs;
    }
    float ivn = invd[node];
    if (g == 0) {   // self term, counted once
        float2 v = *(const float2*)&x[(size_t)node * 32 + c0];
        acc.x = fmaf(v.x, ivn, acc.x);
        acc.y = fmaf(v.y, ivn, acc.y);
    }
    acc.x += __shfl_xor(acc.x, 16);
    acc.y += __shfl_xor(acc.y, 16);
    acc.x += __shfl_xor(acc.x, 32);
    acc.y += __shfl_xor(acc.y, 32);
    sacc  += __shfl_xor(sacc, 16);
    sacc  += __shfl_xor(sacc, 32);
    if (lane < 16) *(float2*)&A32[(size_t)node * 32 + c0] = acc;
    if (lane == 0) qv[node] = ivn * (sacc + ivn);
}

// ------------- gemm1: h1s = relu(p*(A32@W01) + q*c01 + b1) * p -------------
// Broadcast design: W01 in LDS, 8-row A-tile in LDS, each thread computes one
// float4 of one row (acc = 4 VGPRs). Grid-stride over row groups.

__global__ __launch_bounds__(256) void gemm1(const float* __restrict__ A,
                                             const float* __restrict__ W,
                                             const float* __restrict__ c01,
                                             const float* __restrict__ b1,
                                             const float* __restrict__ invd,
                                             const float* __restrict__ qv,
                                             float* __restrict__ out, int n) {
    __shared__ float Wl[32][HID];   // 16 KB
    __shared__ float Al[8][32];     // 1 KB
    __shared__ float cb0[HID], cb1[HID];
    const int tid = threadIdx.x;
    for (int i = tid; i < 32 * (HID / 4); i += 256)
        ((float4*)Wl)[i] = ((const float4*)W)[i];
    if (tid < HID) { cb0[tid] = c01[tid]; cb1[tid] = b1[tid]; }

    const int sub = tid >> 5;     // row within group (0..7)
    const int l32 = tid & 31;
    const int c0 = l32 * 4;       // output column quad
    const int ngrp = (n + 7) >> 3;

    for (int g = blockIdx.x; g < ngrp; g += gridDim.x) {
        const int r = (g << 3) + sub;
        __syncthreads();          // prev iter's reads done; W ready (1st iter)
        Al[sub][l32] = (r < n) ? A[(size_t)r * 32 + l32] : 0.f;
        __syncthreads();
        if (r < n) {
            float4 acc = make_float4(0.f, 0.f, 0.f, 0.f);
#pragma unroll
            for (int k = 0; k < 32; ++k) {
                float a = Al[sub][k];                    // LDS broadcast
                float4 w = *(const float4*)&Wl[k][c0];   // 2-way (free)
                acc.x = fmaf(a, w.x, acc.x);
                acc.y = fmaf(a, w.y, acc.y);
                acc.z = fmaf(a, w.z, acc.z);
                acc.w = fmaf(a, w.w, acc.w);
            }
            float p = invd[r];
            float q = qv[r];
            float4 o;
            o.x = fmaxf(fmaf(acc.x, p, fmaf(q, cb0[c0 + 0], cb1[c0 + 0])), 0.f) * p;
            o.y = fmaxf(fmaf(acc.y, p, fmaf(q, cb0[c0 + 1], cb1[c0 + 1])), 0.f) * p;
            o.z = fmaxf(fmaf(acc.z, p, fmaf(q, cb0[c0 + 2], cb1[c0 + 2])), 0.f) * p;
            o.w = fmaxf(fmaf(acc.w, p, fmaf(q, cb0[c0 + 3], cb1[c0 + 3])), 0.f) * p;
            *(float4*)&out[(size_t)r * HID + c0] = o;
        }
    }
}

// ---------- conv-2 aggregation (marked nodes only, compact output) ---------
// G[i] = sum_adj h1s[s] + h1s[nlist[i]]

__global__ __launch_bounds__(256) void k_aggm(const float* __restrict__ t,
                                              const int* __restrict__ offs,
                                              const int* __restrict__ adj,
                                              const int* __restrict__ nlist,
                                              const int* __restrict__ ncnt,
                                              float* __restrict__ G) {
    int wid = threadIdx.x >> 6;
    int lane = threadIdx.x & 63;
    int idx = blockIdx.x * 4 + wid;
    if (idx >= *ncnt) return;
    int node = nlist[idx];
    const int c0 = lane * 2;
    float2 acc = *(const float2*)&t[(size_t)node * HID + c0];
    int j = offs[node];
    const int e = offs[node + 1];
    for (; j + 4 <= e; j += 4) {
        int s0 = adj[j + 0];
        int s1 = adj[j + 1];
        int s2 = adj[j + 2];
        int s3 = adj[j + 3];
        float2 v0 = *(const float2*)&t[(size_t)s0 * HID + c0];
        float2 v1 = *(const float2*)&t[(size_t)s1 * HID + c0];
        float2 v2 = *(const float2*)&t[(size_t)s2 * HID + c0];
        float2 v3 = *(const float2*)&t[(size_t)s3 * HID + c0];
        acc.x += (v0.x + v1.x) + (v2.x + v3.x);
        acc.y += (v0.y + v1.y) + (v2.y + v3.y);
    }
    for (; j < e; ++j) {
        int sj = adj[j];
        float2 v = *(const float2*)&t[(size_t)sj * HID + c0];
        acc.x += v.x;
        acc.y += v.y;
    }
    *(float2*)&G[(size_t)idx * HID + c0] = acc;
}

// ------------- gemm2: h2c = relu(p*(G@W2) + b2), compact rows --------------
// 64x128 tile, 4x8 thread tile (acc = 32 VGPRs), KC=32 x 4 chunks.

__global__ __launch_bounds__(256) void gemm2(const float* __restrict__ G,
                                             const float* __restrict__ W,
                                             const float* __restrict__ b2,
                                             const float* __restrict__ invd,
                                             const int* __restrict__ nlist,
                                             const int* __restrict__ ncnt,
                                             float* __restrict__ out) {
    constexpr int KC = 32;
    constexpr int NCH = HID / KC;
    constexpr int K4 = KC / 4;
    __shared__ float Wl[KC][HID];        // 16 KB
    __shared__ float hT[KC][64 + 4];     // 8.5 KB

    const int m = *ncnt;
    const int tid = threadIdx.x;
    const int row0 = blockIdx.x * 64;
    const int jg = tid & 15;             // col quad (+64 second half)
    const int rg = tid >> 4;             // row quad (0..15 -> rows rg*4..+3)

    float acc[4][8];
#pragma unroll
    for (int a = 0; a < 4; ++a)
#pragma unroll
        for (int b = 0; b < 8; ++b) acc[a][b] = 0.f;

    for (int ch = 0; ch < NCH; ++ch) {
        for (int i = tid; i < KC * (HID / 4); i += 256)
            ((float4*)Wl)[i] = ((const float4*)(W + (size_t)ch * KC * HID))[i];
        for (int i = tid; i < 64 * K4; i += 256) {
            int k4 = i & (K4 - 1);
            int r = i / K4;
            int gr = row0 + r;
            float4 v = make_float4(0.f, 0.f, 0.f, 0.f);
            if (gr < m) v = *(const float4*)&G[(size_t)gr * HID + ch * KC + k4 * 4];
            hT[k4 * 4 + 0][r] = v.x;
            hT[k4 * 4 + 1][r] = v.y;
            hT[k4 * 4 + 2][r] = v.z;
            hT[k4 * 4 + 3][r] = v.w;
        }
        __syncthreads();
#pragma unroll
        for (int k = 0; k < KC; ++k) {
            float4 hh = *(const float4*)&hT[k][rg * 4];
            float4 w0 = *(const float4*)&Wl[k][jg * 4];
            float4 w1 = *(const float4*)&Wl[k][64 + jg * 4];
            float hr[4] = {hh.x, hh.y, hh.z, hh.w};
            float wc[8] = {w0.x, w0.y, w0.z, w0.w, w1.x, w1.y, w1.z, w1.w};
#pragma unroll
            for (int a = 0; a < 4; ++a)
#pragma unroll
                for (int b = 0; b < 8; ++b) acc[a][b] = fmaf(hr[a], wc[b], acc[a][b]);
        }
        __syncthreads();
    }

    float bj[8];
#pragma unroll
    for (int p = 0; p < 4; ++p) {
        bj[p]     = b2[jg * 4 + p];
        bj[4 + p] = b2[64 + jg * 4 + p];
    }
#pragma unroll
    for (int a = 0; a < 4; ++a) {
        int gr = row0 + rg * 4 + a;
        if (gr >= m) continue;
        float p = invd[nlist[gr]];
        float* po = out + (size_t)gr * HID;
        float4 s0 = make_float4(fmaxf(fmaf(acc[a][0], p, bj[0]), 0.f),
                                fmaxf(fmaf(acc[a][1], p, bj[1]), 0.f),
                                fmaxf(fmaf(acc[a][2], p, bj[2]), 0.f),
                                fmaxf(fmaf(acc[a][3], p, bj[3]), 0.f));
        float4 s1 = make_float4(fmaxf(fmaf(acc[a][4], p, bj[4]), 0.f),
                                fmaxf(fmaf(acc[a][5], p, bj[5]), 0.f),
                                fmaxf(fmaf(acc[a][6], p, bj[6]), 0.f),
                                fmaxf(fmaf(acc[a][7], p, bj[7]), 0.f));
        *(float4*)&po[jg * 4] = s0;
        *(float4*)&po[64 + jg * 4] = s1;
    }
}

// ------------------------------- head --------------------------------------

__global__ __launch_bounds__(1024) void k_head(const float* __restrict__ h2c,
                                               const int* __restrict__ cidx,
                                               const int* __restrict__ smap,
                                               const float* __restrict__ noise,
                                               const float* __restrict__ Wmu,
                                               const float* __restrict__ bmu,
                                               const float* __restrict__ Wls,
                                               const float* __restrict__ bls,
                                               float* __restrict__ out, int ns) {
    __shared__ float part[16];
    int wid = threadIdx.x >> 6;
    int lane = threadIdx.x & 63;
    int i = blockIdx.x * 16 + wid;
    float lp = 0.f;
    if (i < ns) {
        int m = cidx[smap[i]];
        float2 z = *(const float2*)&h2c[(size_t)m * HID + lane * 2];
        float2 wm = *(const float2*)&Wmu[lane * 2];
        float2 wl = *(const float2*)&Wls[lane * 2];
        float dmu = z.x * wm.x + z.y * wm.y;
        float dls = z.x * wl.x + z.y * wl.y;
#pragma unroll
        for (int off = 32; off; off >>= 1) {
            dmu += __shfl_xor(dmu, off);
            dls += __shfl_xor(dls, off);
        }
        float mu = dmu + bmu[0];
        float ls = fminf(fmaxf(dls + bls[0], -20.f), 2.f);
        float nz = noise[i];
        float u = fmaf(expf(ls), nz, mu);
        float a = tanhf(u);
        if (lane == 0) {
            out[i] = a;
            lp = (-0.5f * nz * nz - ls - 0.91893853320467274f)
                 - logf(1.0f - a * a + 1e-6f);
        }
    }
    if (lane == 0) part[wid] = lp;
    __syncthreads();
    if (wid == 0) {
        float v = (lane < 16) ? part[lane] : 0.f;
#pragma unroll
        for (int off = 32; off; off >>= 1) v += __shfl_xor(v, off);
        if (lane == 0) atomicAdd(&out[ns], v);
    }
}

// ------------------------------ launcher -----------------------------------

static inline size_t align256(size_t x) { return (x + 255) & ~(size_t)255; }

extern "C" void kernel_launch(void* const* d_in, const int* in_sizes, int n_in,
                              void* d_out, int out_size, void* d_ws, size_t ws_size,
                              hipStream_t stream) {
    const float* x    = (const float*)d_in[0];
    const int*   ei   = (const int*)d_in[1];
    const int*   smap = (const int*)d_in[2];
    const float* noise= (const float*)d_in[3];
    const float* W_in = (const float*)d_in[4];
    const float* b_in = (const float*)d_in[5];
    const float* W1   = (const float*)d_in[6];
    const float* b1   = (const float*)d_in[7];
    const float* W2   = (const float*)d_in[8];
    const float* b2   = (const float*)d_in[9];
    const float* Wmu  = (const float*)d_in[10];
    const float* bmu  = (const float*)d_in[11];
    const float* Wls  = (const float*)d_in[12];
    const float* bls  = (const float*)d_in[13];
    float* out = (float*)d_out;

    const int n  = in_sizes[0] / 32;   // N_NODES
    const int E  = in_sizes[1] / 2;    // N_EDGES
    const int ns = in_sizes[2];        // N_SGEN
    const int* row = ei;
    const int* col = ei + E;
    const int nb = (n + 63) / 64;      // buckets (<= MAXB)

    char* ws = (char*)d_ws;
    float* h1s  = (float*)ws;                 ws += align256((size_t)n * HID * 4);
    float* A32  = (float*)ws;                 ws += align256((size_t)n * 32 * 4);
    float* qv   = (float*)ws;                 ws += align256((size_t)n * 4);
    float* G    = (float*)ws;                 ws += align256((size_t)ns * HID * 4);
    float* h2c  = (float*)ws;                 ws += align256((size_t)ns * HID * 4);
    int* bcnt    = (int*)ws;                  ws += align256(MAXB * 4);
    int* bstart  = (int*)ws;                  ws += align256((MAXB + 1) * 4);
    int* bcursor = (int*)ws;                  ws += align256(MAXB * 4);
    int* nodeoffs= (int*)ws;                  ws += align256(((size_t)n + 1) * 4);
    float* invd  = (float*)ws;                ws += align256((size_t)n * 4);
    unsigned char* mark = (unsigned char*)ws; ws += align256((size_t)n + 4);
    int* ncnt   = (int*)(mark + n);           // zeroed together with mark
    int* nlist  = (int*)ws;                   ws += align256((size_t)ns * 4);
    int* cidx   = (int*)ws;                   ws += align256((size_t)n * 4);
    float* W01  = (float*)ws;                 ws += align256(32 * HID * 4);
    float* c01  = (float*)ws;                 ws += align256(HID * 4);
    int* adj2   = (int*)ws;                   ws += align256((size_t)E * 4);
    // adjp aliases h1s head: dead before gemm1 writes h1s (stream-ordered).
    unsigned int* adjp = (unsigned int*)h1s;

    // --- histograms + marks ---
    hipMemsetAsync(bcnt, 0, MAXB * 4, stream);
    hipMemsetAsync(mark, 0, (size_t)n + 4, stream);
    k_bhist<<<(E + CHUNK - 1) / CHUNK, 512, 0, stream>>>(col, bcnt, E);
    k_mark<<<(ns + 255) / 256, 256, 0, stream>>>(smap, mark, ns);

    // --- CSR build: scan -> partition -> bucket-local sort ---
    k_bscan<<<1, 1024, 0, stream>>>(bcnt, bstart, bcursor, nodeoffs, n, nb);
    k_w01<<<33, 128, 0, stream>>>(W_in, b_in, W1, W01, c01);
    k_binpack<<<(E + CHUNK - 1) / CHUNK, 512, 0, stream>>>(row, col, bcursor, adjp, E);
    k_bsort<<<nb, 512, 0, stream>>>(adjp, bstart, adj2, nodeoffs, invd, n);
    k_compact<<<(n + 255) / 256, 256, 0, stream>>>(mark, nlist, cidx, ncnt, n);

    const int ablocks = (n + 3) / 4;
    const int mblocks = (ns + 3) / 4;       // marked-node upper bound
    const int g2blocks = (ns + 63) / 64;
    int g1blocks = (n + 7) / 8;
    if (g1blocks > 2048) g1blocks = 2048;

    // --- network ---
    k_agg32<<<ablocks, 256, 0, stream>>>(x, invd, nodeoffs, adj2, A32, qv, n);
    gemm1<<<g1blocks, 256, 0, stream>>>(A32, W01, c01, b1, invd, qv, h1s, n);
    k_aggm<<<mblocks, 256, 0, stream>>>(h1s, nodeoffs, adj2, nlist, ncnt, G);
    gemm2<<<g2blocks, 256, 0, stream>>>(G, W2, b2, invd, nlist, ncnt, h2c);

    // --- head ---
    hipMemsetAsync(out + ns, 0, 4, stream);
    k_head<<<(ns + 15) / 16, 1024, 0, stream>>>(h2c, cidx, smap, noise,
                                                Wmu, bmu, Wls, bls, out, ns);
}

// Round 11
// 324.997 us; speedup vs baseline: 1.7691x; 1.0890x over previous
//
#include <hip/hip_runtime.h>
#include <math.h>

// ---------------------------------------------------------------------------
// GraphActor: GCN(2 conv) + gaussian-tanh head on MI355X.
//
// Round-11: high-MLP gathers (r10's k_agg32 was latency-bound: 80us at 16%
// HBM / 18% VALU / 72% occ -> only 4 neighbor-gathers in flight).
//   agg32: lane l preloads adj[s+l] (coalesced) + invd gather (64-wide MLP);
//          8 groups x 8 lanes x float4 walk neighbors via __shfl broadcast
//          (8 row-gathers in flight, no adj dependency in loop).
//   aggm:  same preload+shfl trick, 64 lanes/row, 4-unrolled uniform loop.
//   rest:  CSR build + gemm1 (broadcast, low-VGPR) + gemm2 + head (validated).
// ---------------------------------------------------------------------------

#define HID 128
#define CHUNK 4096   // edges per binpack/bhist block
#define MAXB 2048    // max buckets (n <= 131072)
#define BMAX 2048    // max edges per bucket (E/nb ~ 1024, sd 32 -> safe)

// ----------------------- bucket histogram (LDS) ----------------------------

__global__ __launch_bounds__(512) void k_bhist(const int* __restrict__ col,
                                               int* __restrict__ bcnt, int E) {
    __shared__ int h[MAXB];
    const int t = threadIdx.x;
    for (int b = t; b < MAXB; b += 512) h[b] = 0;
    __syncthreads();
    const int base = blockIdx.x * CHUNK;
    const int cnt = min(CHUNK, E - base);
    for (int i = t; i < cnt; i += 512) atomicAdd(&h[col[base + i] >> 6], 1);
    __syncthreads();
    for (int b = t; b < MAXB; b += 512)
        if (h[b]) atomicAdd(&bcnt[b], h[b]);
}

__global__ void k_mark(const int* __restrict__ smap, unsigned char* __restrict__ mark, int ns) {
    int i = blockIdx.x * 256 + threadIdx.x;
    if (i < ns) mark[smap[i]] = 1;
}

__global__ void k_compact(const unsigned char* __restrict__ mark, int* __restrict__ nlist,
                          int* __restrict__ cidx, int* __restrict__ ncnt, int n) {
    int i = blockIdx.x * 256 + threadIdx.x;
    if (i < n && mark[i]) {
        int p = atomicAdd(ncnt, 1);
        nlist[p] = i;
        cidx[i] = p;
    }
}

// ---------------- bucket starts: exclusive scan of bcnt --------------------

__global__ __launch_bounds__(1024) void k_bscan(const int* __restrict__ bcnt,
                                                int* __restrict__ bstart,
                                                int* __restrict__ bcursor,
                                                int* __restrict__ nodeoffs,
                                                int n, int nb) {
    __shared__ int sv[1024];
    const int t = threadIdx.x;
    const int a0 = bcnt[2 * t], a1 = bcnt[2 * t + 1];
    sv[t] = a0 + a1;
    __syncthreads();
    for (int off = 1; off < 1024; off <<= 1) {
        int x = (t >= off) ? sv[t - off] : 0;
        __syncthreads();
        sv[t] += x;
        __syncthreads();
    }
    const int ex = t ? sv[t - 1] : 0;   // exclusive pair prefix
    const int b0 = 2 * t, b1 = 2 * t + 1;
    if (b0 <= nb) bstart[b0] = ex;
    if (b1 <= nb) bstart[b1] = ex + a0;
    if (b0 < nb) bcursor[b0] = ex;
    if (b1 < nb) bcursor[b1] = ex + a0;
    if (t == 1023) nodeoffs[n] = sv[1023];   // == E
}

// --------------- binpack: counting-sort partition by bucket ----------------

__global__ __launch_bounds__(512) void k_binpack(const int* __restrict__ row,
                                                 const int* __restrict__ col,
                                                 int* __restrict__ bcursor,
                                                 unsigned int* __restrict__ adjp,
                                                 int E) {
    __shared__ int hist[MAXB];
    __shared__ int rs[MAXB];
    __shared__ int cur[MAXB];
    __shared__ int gb[MAXB];
    __shared__ int sv[512];
    __shared__ unsigned int sorted[CHUNK];
    __shared__ unsigned short bid[CHUNK];

    const int t = threadIdx.x;
    const int base = blockIdx.x * CHUNK;
    const int cnt = min(CHUNK, E - base);

    for (int b = t; b < MAXB; b += 512) hist[b] = 0;
    __syncthreads();
    for (int i = t; i < cnt; i += 512) atomicAdd(&hist[col[base + i] >> 6], 1);
    __syncthreads();

    const int q0 = t * 4;
    int h0 = hist[q0], h1 = hist[q0 + 1], h2 = hist[q0 + 2], h3 = hist[q0 + 3];
    sv[t] = h0 + h1 + h2 + h3;
    __syncthreads();
    for (int off = 1; off < 512; off <<= 1) {
        int x = (t >= off) ? sv[t - off] : 0;
        __syncthreads();
        sv[t] += x;
        __syncthreads();
    }
    int ex = t ? sv[t - 1] : 0;
    rs[q0] = ex;
    rs[q0 + 1] = ex + h0;
    rs[q0 + 2] = ex + h0 + h1;
    rs[q0 + 3] = ex + h0 + h1 + h2;
#pragma unroll
    for (int j = 0; j < 4; ++j) {
        int b = q0 + j;
        cur[b] = rs[b];
        gb[b] = hist[b] ? atomicAdd(&bcursor[b], hist[b]) : 0;
    }
    __syncthreads();

    for (int i = t; i < cnt; i += 512) {
        int c = col[base + i];
        unsigned int r = (unsigned int)row[base + i];
        int b = c >> 6;
        int pos = atomicAdd(&cur[b], 1);
        sorted[pos] = ((unsigned int)(c & 63) << 17) | r;
        bid[pos] = (unsigned short)b;
    }
    __syncthreads();

    for (int i = t; i < cnt; i += 512) {
        int b = bid[i];
        adjp[gb[b] + (i - rs[b])] = sorted[i];
    }
}

// ------- bsort: per-bucket node-sort -> adj2, nodeoffs, invd ---------------

__global__ __launch_bounds__(512) void k_bsort(const unsigned int* __restrict__ adjp,
                                               const int* __restrict__ bstart,
                                               int* __restrict__ adj2,
                                               int* __restrict__ nodeoffs,
                                               float* __restrict__ invd, int n) {
    __shared__ unsigned int ent[BMAX];
    __shared__ int sorted[BMAX];
    __shared__ int h64[64], off64[64], cur64[64];
    const int t = threadIdx.x;
    const int b = blockIdx.x;
    const int s = bstart[b], e = bstart[b + 1];
    const int cnt = min(e - s, BMAX);    // defensive clamp (stat. impossible)
    if (t < 64) h64[t] = 0;
    for (int i = t; i < cnt; i += 512) ent[i] = adjp[s + i];
    __syncthreads();
    for (int i = t; i < cnt; i += 512) atomicAdd(&h64[ent[i] >> 17], 1);
    __syncthreads();
    if (t < 64) off64[t] = h64[t];
    __syncthreads();
    for (int off = 1; off < 64; off <<= 1) {
        int x = 0;
        if (t < 64 && t >= off) x = off64[t - off];
        __syncthreads();
        if (t < 64) off64[t] += x;
        __syncthreads();
    }
    if (t < 64) {
        int excl = off64[t] - h64[t];
        cur64[t] = excl;
        int node = b * 64 + t;
        if (node < n) {
            nodeoffs[node] = s + excl;
            invd[node] = rsqrtf((float)h64[t] + 1.0f);
        }
    }
    __syncthreads();
    for (int i = t; i < cnt; i += 512) {
        unsigned int v = ent[i];
        int pos = atomicAdd(&cur64[v >> 17], 1);
        sorted[pos] = (int)(v & 0x1FFFFu);
    }
    __syncthreads();
    for (int i = t; i < cnt; i += 512) adj2[s + i] = sorted[i];
}

// --------------------- W01 = W_in @ W1, c01 = b_in @ W1 --------------------

__global__ __launch_bounds__(128) void k_w01(const float* __restrict__ W_in,
                                             const float* __restrict__ b_in,
                                             const float* __restrict__ W1,
                                             float* __restrict__ W01,
                                             float* __restrict__ c01) {
    __shared__ float rowl[HID];
    const int j = threadIdx.x;
    const int b = blockIdx.x;
    const float* src = (b < 32) ? (W_in + (size_t)b * HID) : b_in;
    rowl[j] = src[j];
    __syncthreads();
    float acc = 0.f;
#pragma unroll 8
    for (int k = 0; k < HID; ++k) acc = fmaf(rowl[k], W1[(size_t)k * HID + j], acc);
    if (b < 32) W01[(size_t)b * HID + j] = acc;
    else        c01[j] = acc;
}

// ------------- conv-1 aggregation in 32-dim input space --------------------
// A32[n] = sum_{s in adj+self} x[s]*invd[s];  qv[n] = invd[n]*sum invd[s]
// One wave per node. Lane l preloads adj[s+l] + invd (64-wide MLP), then
// 8 groups x 8 lanes (float4 = full row) walk neighbors via shfl broadcast.

__global__ __launch_bounds__(256) void k_agg32(const float* __restrict__ x,
                                               const float* __restrict__ invd,
                                               const int* __restrict__ offs,
                                               const int* __restrict__ adj,
                                               float* __restrict__ A32,
                                               float* __restrict__ qv, int n) {
    int wid = threadIdx.x >> 6;
    int lane = threadIdx.x & 63;
    int node = blockIdx.x * 4 + wid;
    if (node >= n) return;
    const int g = lane >> 3;        // group 0..7
    const int c0 = (lane & 7) * 4;  // channel quad
    const int s = offs[node], e = offs[node + 1];
    const int deg = e - s;
    const int ext = deg + 1;        // + self as virtual neighbor 'deg'
    float4 acc = make_float4(0.f, 0.f, 0.f, 0.f);
    float sacc = 0.f;

    for (int base = 0; base < ext; base += 64) {
        const int li = base + lane;
        int nidx = -1;
        if (li < deg) nidx = adj[s + li];        // coalesced 64-wide
        else if (li == ext - 1) nidx = node;     // self slot
        float ivd_l = (nidx >= 0) ? invd[nidx] : 0.f;   // 64-wide gather
        sacc += ivd_l;
        const int lim = min(64, ext - base);
        const int nIter = (lim + 7) >> 3;        // uniform trip count
        for (int jj = 0; jj < nIter; ++jj) {
            int j = jj * 8 + g;
            int jc = (j < lim) ? j : 0;          // clamp: keep shfl src valid
            int sj = __shfl(nidx, jc);
            float ivs = __shfl(ivd_l, jc);
            if (j < lim && sj >= 0) {
                float4 v = *(const float4*)&x[(size_t)sj * 32 + c0];
                acc.x = fmaf(v.x, ivs, acc.x);
                acc.y = fmaf(v.y, ivs, acc.y);
                acc.z = fmaf(v.z, ivs, acc.z);
                acc.w = fmaf(v.w, ivs, acc.w);
            }
        }
    }
    // reduce acc across the 8 groups (lanes differing in bits 3..5)
#pragma unroll
    for (int off = 8; off <= 32; off <<= 1) {
        acc.x += __shfl_xor(acc.x, off);
        acc.y += __shfl_xor(acc.y, off);
        acc.z += __shfl_xor(acc.z, off);
        acc.w += __shfl_xor(acc.w, off);
    }
    // reduce sacc across all 64 lanes
#pragma unroll
    for (int off = 1; off <= 32; off <<= 1) sacc += __shfl_xor(sacc, off);
    if (lane < 8) *(float4*)&A32[(size_t)node * 32 + c0] = acc;
    if (lane == 0) qv[node] = invd[node] * sacc;   // sacc includes self invd
}

// ------------- gemm1: h1s = relu(p*(A32@W01) + q*c01 + b1) * p -------------
// Broadcast design: W01 in LDS, 8-row A-tile in LDS, each thread computes one
// float4 of one row (acc = 4 VGPRs). Grid-stride over row groups.

__global__ __launch_bounds__(256) void gemm1(const float* __restrict__ A,
                                             const float* __restrict__ W,
                                             const float* __restrict__ c01,
                                             const float* __restrict__ b1,
                                             const float* __restrict__ invd,
                                             const float* __restrict__ qv,
                                             float* __restrict__ out, int n) {
    __shared__ float Wl[32][HID];   // 16 KB
    __shared__ float Al[8][32];     // 1 KB
    __shared__ float cb0[HID], cb1[HID];
    const int tid = threadIdx.x;
    for (int i = tid; i < 32 * (HID / 4); i += 256)
        ((float4*)Wl)[i] = ((const float4*)W)[i];
    if (tid < HID) { cb0[tid] = c01[tid]; cb1[tid] = b1[tid]; }

    const int sub = tid >> 5;     // row within group (0..7)
    const int l32 = tid & 31;
    const int c0 = l32 * 4;       // output column quad
    const int ngrp = (n + 7) >> 3;

    for (int g = blockIdx.x; g < ngrp; g += gridDim.x) {
        const int r = (g << 3) + sub;
        __syncthreads();          // prev iter's reads done; W ready (1st iter)
        Al[sub][l32] = (r < n) ? A[(size_t)r * 32 + l32] : 0.f;
        __syncthreads();
        if (r < n) {
            float4 acc = make_float4(0.f, 0.f, 0.f, 0.f);
#pragma unroll
            for (int k = 0; k < 32; ++k) {
                float a = Al[sub][k];                    // LDS broadcast
                float4 w = *(const float4*)&Wl[k][c0];   // 2-way (free)
                acc.x = fmaf(a, w.x, acc.x);
                acc.y = fmaf(a, w.y, acc.y);
                acc.z = fmaf(a, w.z, acc.z);
                acc.w = fmaf(a, w.w, acc.w);
            }
            float p = invd[r];
            float q = qv[r];
            float4 o;
            o.x = fmaxf(fmaf(acc.x, p, fmaf(q, cb0[c0 + 0], cb1[c0 + 0])), 0.f) * p;
            o.y = fmaxf(fmaf(acc.y, p, fmaf(q, cb0[c0 + 1], cb1[c0 + 1])), 0.f) * p;
            o.z = fmaxf(fmaf(acc.z, p, fmaf(q, cb0[c0 + 2], cb1[c0 + 2])), 0.f) * p;
            o.w = fmaxf(fmaf(acc.w, p, fmaf(q, cb0[c0 + 3], cb1[c0 + 3])), 0.f) * p;
            *(float4*)&out[(size_t)r * HID + c0] = o;
        }
    }
}

// ---------- conv-2 aggregation (marked nodes only, compact output) ---------
// G[i] = sum_adj h1s[s] + h1s[nlist[i]].  Lane l preloads adj[s+l]; uniform
// 4-unrolled shfl loop -> no adj dependency, gathers stay in flight.

__global__ __launch_bounds__(256) void k_aggm(const float* __restrict__ t,
                                              const int* __restrict__ offs,
                                              const int* __restrict__ adj,
                                              const int* __restrict__ nlist,
                                              const int* __restrict__ ncnt,
                                              float* __restrict__ G) {
    int wid = threadIdx.x >> 6;
    int lane = threadIdx.x & 63;
    int idx = blockIdx.x * 4 + wid;
    if (idx >= *ncnt) return;
    int node = nlist[idx];
    const int c0 = lane * 2;
    const int s = offs[node], e = offs[node + 1];
    const int deg = e - s;
    float2 acc = *(const float2*)&t[(size_t)node * HID + c0];   // self
    for (int base = 0; base < deg; base += 64) {
        const int li = base + lane;
        int al = (li < deg) ? adj[s + li] : -1;   // coalesced preload
        const int lim = min(64, deg - base);
        int j = 0;
        for (; j + 4 <= lim; j += 4) {
            int s0 = __shfl(al, j + 0);
            int s1 = __shfl(al, j + 1);
            int s2 = __shfl(al, j + 2);
            int s3 = __shfl(al, j + 3);
            float2 v0 = *(const float2*)&t[(size_t)s0 * HID + c0];
            float2 v1 = *(const float2*)&t[(size_t)s1 * HID + c0];
            float2 v2 = *(const float2*)&t[(size_t)s2 * HID + c0];
            float2 v3 = *(const float2*)&t[(size_t)s3 * HID + c0];
            acc.x += (v0.x + v1.x) + (v2.x + v3.x);
            acc.y += (v0.y + v1.y) + (v2.y + v3.y);
        }
        for (; j < lim; ++j) {
            int sj = __shfl(al, j);
            float2 v = *(const float2*)&t[(size_t)sj * HID + c0];
            acc.x += v.x;
            acc.y += v.y;
        }
    }
    *(float2*)&G[(size_t)idx * HID + c0] = acc;
}

// ------------- gemm2: h2c = relu(p*(G@W2) + b2), compact rows --------------
// 64x128 tile, 4x8 thread tile (acc = 32 VGPRs), KC=32 x 4 chunks.

__global__ __launch_bounds__(256) void gemm2(const float* __restrict__ G,
                                             const float* __restrict__ W,
                                             const float* __restrict__ b2,
                                             const float* __restrict__ invd,
                                             const int* __restrict__ nlist,
                                             const int* __restrict__ ncnt,
                                             float* __restrict__ out) {
    constexpr int KC = 32;
    constexpr int NCH = HID / KC;
    constexpr int K4 = KC / 4;
    __shared__ float Wl[KC][HID];        // 16 KB
    __shared__ float hT[KC][64 + 4];     // 8.5 KB

    const int m = *ncnt;
    const int tid = threadIdx.x;
    const int row0 = blockIdx.x * 64;
    const int jg = tid & 15;             // col quad (+64 second half)
    const int rg = tid >> 4;             // row quad (0..15 -> rows rg*4..+3)

    float acc[4][8];
#pragma unroll
    for (int a = 0; a < 4; ++a)
#pragma unroll
        for (int b = 0; b < 8; ++b) acc[a][b] = 0.f;

    for (int ch = 0; ch < NCH; ++ch) {
        for (int i = tid; i < KC * (HID / 4); i += 256)
            ((float4*)Wl)[i] = ((const float4*)(W + (size_t)ch * KC * HID))[i];
        for (int i = tid; i < 64 * K4; i += 256) {
            int k4 = i & (K4 - 1);
            int r = i / K4;
            int gr = row0 + r;
            float4 v = make_float4(0.f, 0.f, 0.f, 0.f);
            if (gr < m) v = *(const float4*)&G[(size_t)gr * HID + ch * KC + k4 * 4];
            hT[k4 * 4 + 0][r] = v.x;
            hT[k4 * 4 + 1][r] = v.y;
            hT[k4 * 4 + 2][r] = v.z;
            hT[k4 * 4 + 3][r] = v.w;
        }
        __syncthreads();
#pragma unroll
        for (int k = 0; k < KC; ++k) {
            float4 hh = *(const float4*)&hT[k][rg * 4];
            float4 w0 = *(const float4*)&Wl[k][jg * 4];
            float4 w1 = *(const float4*)&Wl[k][64 + jg * 4];
            float hr[4] = {hh.x, hh.y, hh.z, hh.w};
            float wc[8] = {w0.x, w0.y, w0.z, w0.w, w1.x, w1.y, w1.z, w1.w};
#pragma unroll
            for (int a = 0; a < 4; ++a)
#pragma unroll
                for (int b = 0; b < 8; ++b) acc[a][b] = fmaf(hr[a], wc[b], acc[a][b]);
        }
        __syncthreads();
    }

    float bj[8];
#pragma unroll
    for (int p = 0; p < 4; ++p) {
        bj[p]     = b2[jg * 4 + p];
        bj[4 + p] = b2[64 + jg * 4 + p];
    }
#pragma unroll
    for (int a = 0; a < 4; ++a) {
        int gr = row0 + rg * 4 + a;
        if (gr >= m) continue;
        float p = invd[nlist[gr]];
        float* po = out + (size_t)gr * HID;
        float4 s0 = make_float4(fmaxf(fmaf(acc[a][0], p, bj[0]), 0.f),
                                fmaxf(fmaf(acc[a][1], p, bj[1]), 0.f),
                                fmaxf(fmaf(acc[a][2], p, bj[2]), 0.f),
                                fmaxf(fmaf(acc[a][3], p, bj[3]), 0.f));
        float4 s1 = make_float4(fmaxf(fmaf(acc[a][4], p, bj[4]), 0.f),
                                fmaxf(fmaf(acc[a][5], p, bj[5]), 0.f),
                                fmaxf(fmaf(acc[a][6], p, bj[6]), 0.f),
                                fmaxf(fmaf(acc[a][7], p, bj[7]), 0.f));
        *(float4*)&po[jg * 4] = s0;
        *(float4*)&po[64 + jg * 4] = s1;
    }
}

// ------------------------------- head --------------------------------------

__global__ __launch_bounds__(1024) void k_head(const float* __restrict__ h2c,
                                               const int* __restrict__ cidx,
                                               const int* __restrict__ smap,
                                               const float* __restrict__ noise,
                                               const float* __restrict__ Wmu,
                                               const float* __restrict__ bmu,
                                               const float* __restrict__ Wls,
                                               const float* __restrict__ bls,
                                               float* __restrict__ out, int ns) {
    __shared__ float part[16];
    int wid = threadIdx.x >> 6;
    int lane = threadIdx.x & 63;
    int i = blockIdx.x * 16 + wid;
    float lp = 0.f;
    if (i < ns) {
        int m = cidx[smap[i]];
        float2 z = *(const float2*)&h2c[(size_t)m * HID + lane * 2];
        float2 wm = *(const float2*)&Wmu[lane * 2];
        float2 wl = *(const float2*)&Wls[lane * 2];
        float dmu = z.x * wm.x + z.y * wm.y;
        float dls = z.x * wl.x + z.y * wl.y;
#pragma unroll
        for (int off = 32; off; off >>= 1) {
            dmu += __shfl_xor(dmu, off);
            dls += __shfl_xor(dls, off);
        }
        float mu = dmu + bmu[0];
        float ls = fminf(fmaxf(dls + bls[0], -20.f), 2.f);
        float nz = noise[i];
        float u = fmaf(expf(ls), nz, mu);
        float a = tanhf(u);
        if (lane == 0) {
            out[i] = a;
            lp = (-0.5f * nz * nz - ls - 0.91893853320467274f)
                 - logf(1.0f - a * a + 1e-6f);
        }
    }
    if (lane == 0) part[wid] = lp;
    __syncthreads();
    if (wid == 0) {
        float v = (lane < 16) ? part[lane] : 0.f;
#pragma unroll
        for (int off = 32; off; off >>= 1) v += __shfl_xor(v, off);
        if (lane == 0) atomicAdd(&out[ns], v);
    }
}

// ------------------------------ launcher -----------------------------------

static inline size_t align256(size_t x) { return (x + 255) & ~(size_t)255; }

extern "C" void kernel_launch(void* const* d_in, const int* in_sizes, int n_in,
                              void* d_out, int out_size, void* d_ws, size_t ws_size,
                              hipStream_t stream) {
    const float* x    = (const float*)d_in[0];
    const int*   ei   = (const int*)d_in[1];
    const int*   smap = (const int*)d_in[2];
    const float* noise= (const float*)d_in[3];
    const float* W_in = (const float*)d_in[4];
    const float* b_in = (const float*)d_in[5];
    const float* W1   = (const float*)d_in[6];
    const float* b1   = (const float*)d_in[7];
    const float* W2   = (const float*)d_in[8];
    const float* b2   = (const float*)d_in[9];
    const float* Wmu  = (const float*)d_in[10];
    const float* bmu  = (const float*)d_in[11];
    const float* Wls  = (const float*)d_in[12];
    const float* bls  = (const float*)d_in[13];
    float* out = (float*)d_out;

    const int n  = in_sizes[0] / 32;   // N_NODES
    const int E  = in_sizes[1] / 2;    // N_EDGES
    const int ns = in_sizes[2];        // N_SGEN
    const int* row = ei;
    const int* col = ei + E;
    const int nb = (n + 63) / 64;      // buckets (<= MAXB)

    char* ws = (char*)d_ws;
    float* h1s  = (float*)ws;                 ws += align256((size_t)n * HID * 4);
    float* A32  = (float*)ws;                 ws += align256((size_t)n * 32 * 4);
    float* qv   = (float*)ws;                 ws += align256((size_t)n * 4);
    float* G    = (float*)ws;                 ws += align256((size_t)ns * HID * 4);
    float* h2c  = (float*)ws;                 ws += align256((size_t)ns * HID * 4);
    int* bcnt    = (int*)ws;                  ws += align256(MAXB * 4);
    int* bstart  = (int*)ws;                  ws += align256((MAXB + 1) * 4);
    int* bcursor = (int*)ws;                  ws += align256(MAXB * 4);
    int* nodeoffs= (int*)ws;                  ws += align256(((size_t)n + 1) * 4);
    float* invd  = (float*)ws;                ws += align256((size_t)n * 4);
    unsigned char* mark = (unsigned char*)ws; ws += align256((size_t)n + 4);
    int* ncnt   = (int*)(mark + n);           // zeroed together with mark
    int* nlist  = (int*)ws;                   ws += align256((size_t)ns * 4);
    int* cidx   = (int*)ws;                   ws += align256((size_t)n * 4);
    float* W01  = (float*)ws;                 ws += align256(32 * HID * 4);
    float* c01  = (float*)ws;                 ws += align256(HID * 4);
    int* adj2   = (int*)ws;                   ws += align256((size_t)E * 4);
    // adjp aliases h1s head: dead before gemm1 writes h1s (stream-ordered).
    unsigned int* adjp = (unsigned int*)h1s;

    // --- histograms + marks ---
    hipMemsetAsync(bcnt, 0, MAXB * 4, stream);
    hipMemsetAsync(mark, 0, (size_t)n + 4, stream);
    k_bhist<<<(E + CHUNK - 1) / CHUNK, 512, 0, stream>>>(col, bcnt, E);
    k_mark<<<(ns + 255) / 256, 256, 0, stream>>>(smap, mark, ns);

    // --- CSR build: scan -> partition -> bucket-local sort ---
    k_bscan<<<1, 1024, 0, stream>>>(bcnt, bstart, bcursor, nodeoffs, n, nb);
    k_w01<<<33, 128, 0, stream>>>(W_in, b_in, W1, W01, c01);
    k_binpack<<<(E + CHUNK - 1) / CHUNK, 512, 0, stream>>>(row, col, bcursor, adjp, E);
    k_bsort<<<nb, 512, 0, stream>>>(adjp, bstart, adj2, nodeoffs, invd, n);
    k_compact<<<(n + 255) / 256, 256, 0, stream>>>(mark, nlist, cidx, ncnt, n);

    const int ablocks = (n + 3) / 4;
    const int mblocks = (ns + 3) / 4;       // marked-node upper bound
    const int g2blocks = (ns + 63) / 64;
    int g1blocks = (n + 7) / 8;
    if (g1blocks > 2048) g1blocks = 2048;

    // --- network ---
    k_agg32<<<ablocks, 256, 0, stream>>>(x, invd, nodeoffs, adj2, A32, qv, n);
    gemm1<<<g1blocks, 256, 0, stream>>>(A32, W01, c01, b1, invd, qv, h1s, n);
    k_aggm<<<mblocks, 256, 0, stream>>>(h1s, nodeoffs, adj2, nlist, ncnt, G);
    gemm2<<<g2blocks, 256, 0, stream>>>(G, W2, b2, invd, nlist, ncnt, h2c);

    // --- head ---
    hipMemsetAsync(out + ns, 0, 4, stream);
    k_head<<<(ns + 15) / 16, 1024, 0, stream>>>(h2c, cidx, smap, noise,
                                                Wmu, bmu, Wls, bls, out, ns);
}